// Round 7
// baseline (498.491 us; speedup 1.0000x reference)
//
#include <hip/hip_runtime.h>
#include <stdint.h>

#define NN 4096
#define SS 16

// fixed ws float offsets
#define OFF_XYZ1F 0          // 4*3*4096 f32
#define OFF_XYZ2F 49152      // 4*3*4096 f32
#define OFF_N1    98304      // 4*4096 f32 (dead after knn -> nb2 of feat2 points)
#define OFF_N2    114688     // 4*4096 f32 (dead after knn -> folds)
#define OFF_F2T   131072     // feat2 transpose [b][n][c]: u16 (compact) or f32 (big)
#define WS_MIN_FLOATS 1966080ull

// fold outputs (dead-after-knn regions, written by k_fold AFTER k_knn)
#define OFF_NB2 98304    // ||feat2[b][:,n]||^2, 16384 floats (over N1)
#define OFF_A2  114688   // (W1Wq - M*Wva)  [c][h] 1024
#define OFF_G   115712   // (M*Wvb)         [c][h] 1024
#define OFF_P5  116736   // [p][h] 80
#define OFF_MBP 116816   // M*bp1 [h] 16
#define OFF_C2  116832   // Wk2^T*Wq2 [c][o] 4096
// AoS candidate arrays (x,y,z,norm) live in the P2N region: written by k_prep,
// consumed by k_knn, then overwritten by k_group1's P2N output (stream-ordered).
//
// PITFALL (r3-r5 bisect): k_knn's stored distance values are numerics-pinned to
// the reference's near-tie ordering. Caching pass-1 distances for reuse in pass 2
// (a "provably bit-identical" refactor) changed emitted FP code enough to flip a
// near-tie -> wrong neighbor set -> absmax 0.125. DO NOT alter the k_knn distance
// computation/storage path.

typedef const uint16_t* u16p;

__device__ __forceinline__ float bf2f(uint16_t u) {
  return __uint_as_float(((uint32_t)u) << 16);
}
__device__ __forceinline__ uint16_t f2bf(float f) {
  uint32_t x = __float_as_uint(f);
  uint32_t r = (x + 0x7FFFu + ((x >> 16) & 1u)) >> 16;
  return (uint16_t)r;
}
__device__ __forceinline__ float ldi(const void* p, int i, int f32m) {
  return f32m ? ((const float*)p)[i] : bf2f(((const uint16_t*)p)[i]);
}
__device__ __forceinline__ int detect_f32(const uint16_t* probe) {
  int lane = threadIdx.x & 63;
  float a = bf2f(probe[lane]);
  float b = bf2f(probe[lane + 64]);
  int bad = (!(fabsf(a) <= 1e4f)) || (!(fabsf(b) <= 1e4f));
  return __any(bad) ? 1 : 0;
}

// 16-wide dual dot (f32 row regs)
__device__ __forceinline__ void dot16f(const float4& A0, const float4& A1,
                                       const float4& A2r, const float4& A3,
                                       const float* Gr, const float* f1r,
                                       float& gl, float& dp) {
  gl = fmaf(Gr[0], A0.x, gl);   dp = fmaf(f1r[0], A0.x, dp);
  gl = fmaf(Gr[1], A0.y, gl);   dp = fmaf(f1r[1], A0.y, dp);
  gl = fmaf(Gr[2], A0.z, gl);   dp = fmaf(f1r[2], A0.z, dp);
  gl = fmaf(Gr[3], A0.w, gl);   dp = fmaf(f1r[3], A0.w, dp);
  gl = fmaf(Gr[4], A1.x, gl);   dp = fmaf(f1r[4], A1.x, dp);
  gl = fmaf(Gr[5], A1.y, gl);   dp = fmaf(f1r[5], A1.y, dp);
  gl = fmaf(Gr[6], A1.z, gl);   dp = fmaf(f1r[6], A1.z, dp);
  gl = fmaf(Gr[7], A1.w, gl);   dp = fmaf(f1r[7], A1.w, dp);
  gl = fmaf(Gr[8], A2r.x, gl);  dp = fmaf(f1r[8], A2r.x, dp);
  gl = fmaf(Gr[9], A2r.y, gl);  dp = fmaf(f1r[9], A2r.y, dp);
  gl = fmaf(Gr[10], A2r.z, gl); dp = fmaf(f1r[10], A2r.z, dp);
  gl = fmaf(Gr[11], A2r.w, gl); dp = fmaf(f1r[11], A2r.w, dp);
  gl = fmaf(Gr[12], A3.x, gl);  dp = fmaf(f1r[12], A3.x, dp);
  gl = fmaf(Gr[13], A3.y, gl);  dp = fmaf(f1r[13], A3.y, dp);
  gl = fmaf(Gr[14], A3.z, gl);  dp = fmaf(f1r[14], A3.z, dp);
  gl = fmaf(Gr[15], A3.w, gl);  dp = fmaf(f1r[15], A3.w, dp);
}

// 16-wide dual dot (bf16 row regs, unpack on the fly)
__device__ __forceinline__ void dot16b(const uint4& U0, const uint4& U1,
                                       const float* Gr, const float* f1r,
                                       float& gl, float& dp) {
  float nv;
  nv = bf2f((uint16_t)(U0.x & 0xFFFF)); gl = fmaf(Gr[0], nv, gl);  dp = fmaf(f1r[0], nv, dp);
  nv = bf2f((uint16_t)(U0.x >> 16));    gl = fmaf(Gr[1], nv, gl);  dp = fmaf(f1r[1], nv, dp);
  nv = bf2f((uint16_t)(U0.y & 0xFFFF)); gl = fmaf(Gr[2], nv, gl);  dp = fmaf(f1r[2], nv, dp);
  nv = bf2f((uint16_t)(U0.y >> 16));    gl = fmaf(Gr[3], nv, gl);  dp = fmaf(f1r[3], nv, dp);
  nv = bf2f((uint16_t)(U0.z & 0xFFFF)); gl = fmaf(Gr[4], nv, gl);  dp = fmaf(f1r[4], nv, dp);
  nv = bf2f((uint16_t)(U0.z >> 16));    gl = fmaf(Gr[5], nv, gl);  dp = fmaf(f1r[5], nv, dp);
  nv = bf2f((uint16_t)(U0.w & 0xFFFF)); gl = fmaf(Gr[6], nv, gl);  dp = fmaf(f1r[6], nv, dp);
  nv = bf2f((uint16_t)(U0.w >> 16));    gl = fmaf(Gr[7], nv, gl);  dp = fmaf(f1r[7], nv, dp);
  nv = bf2f((uint16_t)(U1.x & 0xFFFF)); gl = fmaf(Gr[8], nv, gl);  dp = fmaf(f1r[8], nv, dp);
  nv = bf2f((uint16_t)(U1.x >> 16));    gl = fmaf(Gr[9], nv, gl);  dp = fmaf(f1r[9], nv, dp);
  nv = bf2f((uint16_t)(U1.y & 0xFFFF)); gl = fmaf(Gr[10], nv, gl); dp = fmaf(f1r[10], nv, dp);
  nv = bf2f((uint16_t)(U1.y >> 16));    gl = fmaf(Gr[11], nv, gl); dp = fmaf(f1r[11], nv, dp);
  nv = bf2f((uint16_t)(U1.z & 0xFFFF)); gl = fmaf(Gr[12], nv, gl); dp = fmaf(f1r[12], nv, dp);
  nv = bf2f((uint16_t)(U1.z >> 16));    gl = fmaf(Gr[13], nv, gl); dp = fmaf(f1r[13], nv, dp);
  nv = bf2f((uint16_t)(U1.w & 0xFFFF)); gl = fmaf(Gr[14], nv, gl); dp = fmaf(f1r[14], nv, dp);
  nv = bf2f((uint16_t)(U1.w >> 16));    gl = fmaf(Gr[15], nv, gl); dp = fmaf(f1r[15], nv, dp);
}

// group2 single dot
__device__ __forceinline__ float dotu16(const float4& A0, const float4& A1,
                                        const float4& A2v, const float4& A3,
                                        const float* u16r) {
  float tp = 0.f;
  tp = fmaf(u16r[0], A0.x, tp);   tp = fmaf(u16r[1], A0.y, tp);
  tp = fmaf(u16r[2], A0.z, tp);   tp = fmaf(u16r[3], A0.w, tp);
  tp = fmaf(u16r[4], A1.x, tp);   tp = fmaf(u16r[5], A1.y, tp);
  tp = fmaf(u16r[6], A1.z, tp);   tp = fmaf(u16r[7], A1.w, tp);
  tp = fmaf(u16r[8], A2v.x, tp);  tp = fmaf(u16r[9], A2v.y, tp);
  tp = fmaf(u16r[10], A2v.z, tp); tp = fmaf(u16r[11], A2v.w, tp);
  tp = fmaf(u16r[12], A3.x, tp);  tp = fmaf(u16r[13], A3.y, tp);
  tp = fmaf(u16r[14], A3.z, tp);  tp = fmaf(u16r[15], A3.w, tp);
  return tp;
}

// ---------------- prep: SoA xyz + norms + AoS candidate float4s ----------------
__global__ __launch_bounds__(256) void k_prep_xyz(const void* xyz1, const void* xyz2,
                                                  u16p probe, float* ws, int off_aos) {
  int f32m = detect_f32(probe);
  int t = blockIdx.x * 256 + threadIdx.x;
  int b = t >> 12, n = t & (NN - 1);
  int base = b * 3 * NN + n;
  float x1 = ldi(xyz1, base, f32m), y1 = ldi(xyz1, base + NN, f32m), z1 = ldi(xyz1, base + 2 * NN, f32m);
  float x2 = ldi(xyz2, base, f32m), y2 = ldi(xyz2, base + NN, f32m), z2 = ldi(xyz2, base + 2 * NN, f32m);
  float* x1f = ws + OFF_XYZ1F;
  float* x2f = ws + OFF_XYZ2F;
  x1f[base] = x1; x1f[base + NN] = y1; x1f[base + 2 * NN] = z1;
  x2f[base] = x2; x2f[base + NN] = y2; x2f[base + 2 * NN] = z2;
  float n1v = __fadd_rn(__fadd_rn(__fmul_rn(x1, x1), __fmul_rn(y1, y1)), __fmul_rn(z1, z1));
  float n2v = __fadd_rn(__fadd_rn(__fmul_rn(x2, x2), __fmul_rn(y2, y2)), __fmul_rn(z2, z2));
  ws[OFF_N1 + t] = n1v;
  ws[OFF_N2 + t] = n2v;
  ((float4*)(ws + off_aos))[t]          = make_float4(x2, y2, z2, n2v);  // which=0 cands
  ((float4*)(ws + off_aos + 65536))[t]  = make_float4(x1, y1, z1, n1v);  // which=1 cands
}

// ---------------- transpose feat2 ----------------
__global__ __launch_bounds__(256) void k_transpose(const void* feat2, u16p probe,
                                                   float* ws, int f2cap) {
  __shared__ float tile[64][65];
  int f32m = detect_f32(probe);
  int b = blockIdx.x >> 6;
  int n0 = (blockIdx.x & 63) * 64;
  int tx = threadIdx.x & 63, ty = threadIdx.x >> 6;
#pragma unroll
  for (int i = 0; i < 16; ++i) {
    int c = i * 4 + ty;
    tile[c][tx] = ldi(feat2, (b * 64 + c) * NN + n0 + tx, f32m);
  }
  __syncthreads();
#pragma unroll
  for (int i = 0; i < 16; ++i) {
    int nl = i * 4 + ty;
    size_t di = (size_t)(b * NN + n0 + nl) * 64 + tx;
    float v = tile[tx][nl];
    if (f2cap) ((float*)(ws + OFF_F2T))[di] = v;
    else       ((uint16_t*)(ws + OFF_F2T))[di] = f2bf(v);
  }
}

// ---------------- KNN: wave-per-query, AoS loads, subsample-threshold ----------------
#define KCAP 320
__device__ __forceinline__ float knn_dist4(float4 cc, float qx, float qy, float qz, float q2) {
  float cross = __fadd_rn(__fadd_rn(__fmul_rn(qx, cc.x), __fmul_rn(qy, cc.y)),
                          __fmul_rn(qz, cc.z));
  return __fsub_rn(__fadd_rn(q2, cc.w), __fmul_rn(2.0f, cross));
}

__global__ __launch_bounds__(256) void k_knn(float* ws, int off_i12, int off_i11, int off_aos) {
  __shared__ float sd[4][KCAP];
  __shared__ int   si[4][KCAP];
  __shared__ int   eqbuf[4][16];

  int tid = threadIdx.x;
  int wv = tid >> 6, lane = tid & 63;
  int q = blockIdx.x * 4 + wv;
  int which = q >> 14;
  int b = (q >> 12) & 3;
  int n = q & (NN - 1);

  const float4* cnd = (const float4*)(ws + off_aos + (which ? 65536 : 0)) + b * NN;
  const float* qp = ws + OFF_XYZ1F + b * 3 * NN;
  float qx = qp[n], qy = qp[NN + n], qz = qp[2 * NN + n];
  float q2 = ws[OFF_N1 + b * NN + n];
  const float INF = __builtin_inff();

  float mn = INF;
#pragma unroll 4
  for (int i = 0; i < 16; ++i) {
    float d = knn_dist4(cnd[i * 64 + lane], qx, qy, qz, q2);
    mn = fminf(mn, d);
  }
  // tau0 = 16th smallest of 64 lane minima via full bitonic sort, take lane 15
  float v = mn;
#pragma unroll
  for (int k = 2; k <= 64; k <<= 1) {
#pragma unroll
    for (int j = k >> 1; j > 0; j >>= 1) {
      float other = __shfl_xor(v, j);
      bool up = ((lane & k) == 0);
      bool lower = ((lane & j) == 0);
      v = (up == lower) ? fminf(v, other) : fmaxf(v, other);
    }
  }
  float tau0 = __shfl(v, 15);

  unsigned long long below = (1ull << lane) - 1ull;
  int c = 0;
#pragma unroll 2
  for (int i = 0; i < 64; ++i) {
    int j = i * 64 + lane;
    float d = knn_dist4(cnd[j], qx, qy, qz, q2);
    bool sel = (d <= tau0);
    unsigned long long msk = __ballot(sel);
    int pos = c + __popcll(msk & below);
    if (sel && pos < KCAP) { sd[wv][pos] = d; si[wv][pos] = j; }
    c += __popcll(msk);
  }
  if (c > KCAP) c = KCAP;   // ~e^-50 event; clamp for safety
  __syncthreads();

  float ch[5];
#pragma unroll
  for (int t = 0; t < 5; ++t) ch[t] = INF;
#pragma unroll
  for (int t = 0; t < 5; ++t) {
    int p = t * 64 + lane;
    float x = (p < c) ? sd[wv][p] : INF;
#pragma unroll
    for (int u = 0; u < 5; ++u) {
      float lo = fminf(ch[u], x);
      x = fmaxf(ch[u], x);
      ch[u] = lo;
    }
  }
  float tau = 0.f;
  {
    float h = ch[0];
#pragma unroll 1
    for (int r = 0; r < 16; ++r) {
      float m = h;
#pragma unroll
      for (int msk = 1; msk < 64; msk <<= 1) m = fminf(m, __shfl_xor(m, msk));
      if (r == 15) tau = m;
      unsigned long long win = __ballot(h == m);
      int winner = __ffsll(win) - 1;
      if (lane == winner) {
        ch[0] = ch[1]; ch[1] = ch[2]; ch[2] = ch[3]; ch[3] = ch[4]; ch[4] = INF;
        h = ch[0];
      }
    }
  }

  uint16_t* outp = (uint16_t*)(ws + (which ? off_i11 : off_i12)) + (size_t)(b * NN + n) * SS;
  int c1 = 0, eqc = 0;
#pragma unroll
  for (int t = 0; t < 5; ++t) {
    int p = t * 64 + lane;
    bool act = (p < c);
    float d = act ? sd[wv][p] : INF;
    int j = act ? si[wv][p] : 0;
    bool lt = act && (d < tau);
    bool eq = act && (d == tau);
    unsigned long long mlt = __ballot(lt);
    unsigned long long meq = __ballot(eq);
    int pl = __popcll(mlt & below);
    if (lt) outp[c1 + pl] = (uint16_t)j;
    int pe = __popcll(meq & below);
    if (eq && (eqc + pe) < 16) eqbuf[wv][eqc + pe] = j;
    c1 += __popcll(mlt);
    eqc += __popcll(meq);
  }
  __syncthreads();
  int need = 16 - c1;
  if (lane < need) outp[c1 + lane] = (uint16_t)eqbuf[wv][lane];
}

// ---------------- fold: algebraic precomputes + feat2 norms (66 blocks) ----------------
__global__ __launch_bounds__(256) void k_fold(
    const void* w_q1, const void* w_k1, const void* w_v1, const void* w_mlp1,
    const void* w_pos1, const void* b_pos1, const void* w_q2, const void* w_k2,
    u16p probe, float* ws, int f2cap) {
  int f32m = detect_f32(probe);
  int tid = threadIdx.x;

  if (blockIdx.x >= 2) {
    int p = (blockIdx.x - 2) * 256 + tid;
    const float* f2f32 = (const float*)(ws + OFF_F2T);
    const uint16_t* f2u16 = (const uint16_t*)(ws + OFF_F2T);
    size_t row = (size_t)p * 64;
    float acc = 0.f;
#pragma unroll 8
    for (int c = 0; c < 64; ++c) {
      float v = f2cap ? f2f32[row + c] : bf2f(f2u16[row + c]);
      acc = fmaf(v, v, acc);
    }
    ws[OFF_NB2 + p] = acc;
    return;
  }

  __shared__ float lA[4096];
  __shared__ float lB[2048];   // lW1[0:1024], lM[1024:2048]
  if (blockIdx.x == 1) {
    __shared__ float lQ[4096];
    for (int i = tid; i < 4096; i += 256) { lA[i] = ldi(w_k2, i, f32m); lQ[i] = ldi(w_q2, i, f32m); }
    __syncthreads();
    for (int i = tid; i < 4096; i += 256) {
      int c = i >> 6, o = i & 63;
      float a0 = 0.f, a1 = 0.f, a2 = 0.f, a3 = 0.f;
      for (int a = 0; a < 64; a += 4) {
        a0 = fmaf(lA[a * 64 + o],       lQ[a * 64 + c],       a0);
        a1 = fmaf(lA[(a + 1) * 64 + o], lQ[(a + 1) * 64 + c], a1);
        a2 = fmaf(lA[(a + 2) * 64 + o], lQ[(a + 2) * 64 + c], a2);
        a3 = fmaf(lA[(a + 3) * 64 + o], lQ[(a + 3) * 64 + c], a3);
      }
      ws[OFF_C2 + i] = (a0 + a1) + (a2 + a3);
    }
    return;
  }

  float* lW1 = lB;
  float* lM  = lB + 1024;
  for (int i = tid; i < 1024; i += 256) lW1[i] = ldi(w_mlp1, i, f32m);   // [h][m]
  for (int i = tid; i < 4096; i += 256) lA[i] = ldi(w_k1, i, f32m);      // [m][o]
  __syncthreads();
  for (int i = tid; i < 1024; i += 256) {       // M[h][o] = W1.Wk
    int hh = i >> 6, o = i & 63;
    float acc = 0.f;
    for (int m = 0; m < 64; ++m) acc = fmaf(lW1[hh * 64 + m], lA[m * 64 + o], acc);
    lM[i] = acc;
  }
  __syncthreads();
  float a2acc[4];
  for (int i = tid; i < 4096; i += 256) lA[i] = ldi(w_q1, i, f32m);      // [o][c]
  __syncthreads();
  for (int k = 0; k < 4; ++k) {
    int i = tid + k * 256;
    int c = i >> 4, hh = i & 15;
    float acc = 0.f;
    for (int o = 0; o < 64; ++o) acc = fmaf(lW1[hh * 64 + o], lA[o * 64 + c], acc);
    a2acc[k] = acc;
  }
  __syncthreads();
  for (int i = tid; i < 4096; i += 256) { int o = i >> 6, c = i & 63; lA[o * 64 + c] = ldi(w_v1, o * 131 + c, f32m); }
  __syncthreads();
  for (int k = 0; k < 4; ++k) {
    int i = tid + k * 256;
    int c = i >> 4, hh = i & 15;
    float acc = 0.f;
    for (int o = 0; o < 64; ++o) acc = fmaf(lM[hh * 64 + o], lA[o * 64 + c], acc);
    ws[OFF_A2 + i] = a2acc[k] - acc;
  }
  __syncthreads();
  for (int i = tid; i < 4096; i += 256) { int o = i >> 6, c = i & 63; lA[o * 64 + c] = ldi(w_v1, o * 131 + 64 + c, f32m); }
  __syncthreads();
  for (int i = tid; i < 1024; i += 256) {       // G[c][h] = M*Wvb
    int c = i >> 4, hh = i & 15;
    float acc = 0.f;
    for (int o = 0; o < 64; ++o) acc = fmaf(lM[hh * 64 + o], lA[o * 64 + c], acc);
    ws[OFF_G + i] = acc;
  }
  if (tid < 16) {
    int hh = tid;
    float p0 = 0.f, p1 = 0.f, p2 = 0.f, p3 = 0.f, p4 = 0.f, pb = 0.f;
    for (int o = 0; o < 64; ++o) {
      float m = lM[hh * 64 + o];
      p0 = fmaf(m, ldi(w_pos1, o * 5 + 0, f32m), p0);
      p1 = fmaf(m, ldi(w_pos1, o * 5 + 1, f32m), p1);
      p2 = fmaf(m, ldi(w_v1, o * 131 + 128, f32m) + ldi(w_pos1, o * 5 + 2, f32m), p2);
      p3 = fmaf(m, ldi(w_v1, o * 131 + 129, f32m) + ldi(w_pos1, o * 5 + 3, f32m), p3);
      p4 = fmaf(m, ldi(w_v1, o * 131 + 130, f32m) + ldi(w_pos1, o * 5 + 4, f32m), p4);
      pb = fmaf(m, ldi(b_pos1, o, f32m), pb);
    }
    ws[OFF_P5 + hh] = p0; ws[OFF_P5 + 16 + hh] = p1; ws[OFF_P5 + 32 + hh] = p2;
    ws[OFF_P5 + 48 + hh] = p3; ws[OFF_P5 + 64 + hh] = p4;
    ws[OFF_MBP + hh] = pb;
  }
}

// shared dual-step online-softmax epilogue for group1's s-loop.
// Consumes gl0,dp0,nb0 (step s) and gl1,dp1,nb1 (step s+1); updates m,l,anb,axa,aya,aza.
#define G1_EPI()                                                        \
      gl0 += __shfl_xor(gl0, 16); dp0 += __shfl_xor(dp0, 16);           \
      gl1 += __shfl_xor(gl1, 16); dp1 += __shfl_xor(dp1, 16);           \
      gl0 += __shfl_xor(gl0, 32); dp0 += __shfl_xor(dp0, 32);           \
      gl1 += __shfl_xor(gl1, 32); dp1 += __shfl_xor(dp1, 32);           \
      float4 xd0 = xds4[w][s];                                          \
      float4 xd1 = xds4[w][s + 1];                                      \
      float fn0 = sqrtf(fmaxf(f1n2 - 2.f * dp0 + snb2[w][s], 0.f));     \
      float fn1 = sqrtf(fmaxf(f1n2 - 2.f * dp1 + snb2[w][s + 1], 0.f)); \
      float p50 = p5a * fn0;                                            \
      p50 = fmaf(p5b, xd0.w, p50); p50 = fmaf(p5c, xd0.x, p50);         \
      p50 = fmaf(p5d, xd0.y, p50); p50 = fmaf(p5e, xd0.z, p50);         \
      float p51 = p5a * fn1;                                            \
      p51 = fmaf(p5b, xd1.w, p51); p51 = fmaf(p5c, xd1.x, p51);         \
      p51 = fmaf(p5d, xd1.y, p51); p51 = fmaf(p5e, xd1.z, p51);         \
      float r0 = fmaxf(tb - gl0 - p50, 0.f) * w2r;                      \
      float r1 = fmaxf(tb - gl1 - p51, 0.f) * w2r;                      \
      r0 += __shfl_xor(r0, 1); r1 += __shfl_xor(r1, 1);                 \
      r0 += __shfl_xor(r0, 2); r1 += __shfl_xor(r1, 2);                 \
      r0 += __shfl_xor(r0, 4); r1 += __shfl_xor(r1, 4);                 \
      r0 += __shfl_xor(r0, 8); r1 += __shfl_xor(r1, 8);                 \
      float mnv = fmaxf(fmaxf(m, r0), r1);                              \
      float sc = __expf(m - mnv);                                       \
      float e0 = __expf(r0 - mnv);                                      \
      float e1 = __expf(r1 - mnv);                                      \
      l = fmaf(l, sc, e0 + e1);                                         \
      anb = fmaf(e1, nb1, fmaf(e0, nb0, anb * sc));                     \
      axa = fmaf(e1, xd1.x, fmaf(e0, xd0.x, axa * sc));                 \
      aya = fmaf(e1, xd1.y, fmaf(e0, xd0.y, aya * sc));                 \
      aza = fmaf(e1, xd1.z, fmaf(e0, xd0.z, aza * sc));                 \
      m = mnv;

#define G1_LOADF(A0, A1, A2r, A3, NBV, J) {                             \
      size_t row_ = (size_t)(b * NN + (J)) * 64;                        \
      const float4* r4_ = (const float4*)(f2f32 + row_) + part * 4;     \
      A0 = r4_[0]; A1 = r4_[1]; A2r = r4_[2]; A3 = r4_[3];              \
      NBV = f2f32[row_ + o]; }

#define G1_LOADB(U0, U1, NBU, J) {                                      \
      size_t row_ = (size_t)(b * NN + (J)) * 64;                        \
      const uint4* r4_ = (const uint4*)(f2u16 + row_) + part * 2;       \
      U0 = r4_[0]; U1 = r4_[1]; NBU = f2u16[row_ + o]; }

// ---------------- group1: per-lane slice loads, depth-2 pipelined gather loop ----------------
// launch_bounds (512,2): 2 BLOCKS/CU (CUDA semantics, r8 post-mortem) => 128-VGPR cap.
__global__ __launch_bounds__(512, 2) void k_group1(
    const void* feat1, const void* w_v1, const void* w_mlp2,
    u16p probe, float* ws, int off_p2n, int off_i12, int f2cap) {
  __shared__ float s_wva[4096];    // [c][o]
  __shared__ float s_wvb[4096];    // [c][o]
  __shared__ float s_wvx[192];
  __shared__ float s_A2[1088];     // [c*17+h] padded
  __shared__ float s_G[1088];      // [c*17+h] padded
  __shared__ float s_P5[80];
  __shared__ float s_MBP[16];
  __shared__ float s_w2[16];
  __shared__ float f1s[8][64];
  __shared__ float4 xds4[8][16];   // per s: (dx,dy,dz,norm)
  __shared__ float snb2[8][16];
  __shared__ int   idxs[8][16];

  int f32m = detect_f32(probe);
  int tid = threadIdx.x;
  for (int i = tid; i < 4096; i += 512) {
    int c = i >> 6, o = i & 63;
    s_wva[i] = ldi(w_v1, o * 131 + c, f32m);
    s_wvb[i] = ldi(w_v1, o * 131 + 64 + c, f32m);
  }
  if (tid < 192) { int j = tid >> 6, o = tid & 63; s_wvx[tid] = ldi(w_v1, o * 131 + 128 + j, f32m); }
  for (int i = tid; i < 1024; i += 512) {
    int c = i >> 4, h = i & 15;
    s_A2[c * 17 + h] = ws[OFF_A2 + i];
    s_G[c * 17 + h] = ws[OFF_G + i];
  }
  if (tid < 80) s_P5[tid] = ws[OFF_P5 + tid];
  if (tid < 16) { s_MBP[tid] = ws[OFF_MBP + tid]; s_w2[tid] = ldi(w_mlp2, tid, f32m); }

  int w = tid >> 6, o = tid & 63;
  // XCD-locality remap (r7): hardware round-robins blocks across 8 XCDs, so
  // b = blk&3 pins each XCD to a single batch's f2t/feat1 slice (~2MB, L2-fit).
  // Pure permutation of block->query; per-query FP code/data bit-identical.
  int blk = blockIdx.x;
  int b = blk & 3, n = ((blk >> 2) << 3) + w;
  const float* x1f = ws + OFF_XYZ1F + b * 3 * NN;
  const float* x2f = ws + OFF_XYZ2F + b * 3 * NN;
  const uint16_t* idx12 = (const uint16_t*)(ws + off_i12) + (size_t)(b * NN + n) * SS;
  const float* f2f32 = (const float*)(ws + OFF_F2T);
  const uint16_t* f2u16 = (const uint16_t*)(ws + OFF_F2T);

  float f1o = ldi(feat1, (b * 64 + o) * NN + n, f32m);
  f1s[w][o] = f1o;
  float qx = x1f[n], qy = x1f[NN + n], qz = x1f[2 * NN + n];
  if (o < 16) {
    int j = (int)idx12[o];
    idxs[w][o] = j;
    float dx = __fsub_rn(qx, x2f[j]);
    float dy = __fsub_rn(qy, x2f[NN + j]);
    float dz = __fsub_rn(qz, x2f[2 * NN + j]);
    xds4[w][o] = make_float4(dx, dy, dz, sqrtf(dx * dx + dy * dy + dz * dz));
    snb2[w][o] = ws[OFF_NB2 + b * NN + j];
  }
  __syncthreads();   // only block barrier; below: regs/shfl/read-only LDS

  int h = o & 15, part = o >> 4;
  float Gr[16], f1r[16];
#pragma unroll
  for (int i = 0; i < 16; ++i) {
    int c = part * 16 + i;
    Gr[i] = s_G[c * 17 + h];
    f1r[i] = f1s[w][c];
  }
  float p5a = s_P5[h], p5b = s_P5[16 + h], p5c = s_P5[32 + h], p5d = s_P5[48 + h], p5e = s_P5[64 + h];
  float w2r = s_w2[h];

  float f1n2 = f1o * f1o;
#pragma unroll
  for (int msk = 1; msk < 64; msk <<= 1) f1n2 += __shfl_xor(f1n2, msk);
  float v0 = 0.f, v1 = 0.f, v2 = 0.f, v3 = 0.f;
#pragma unroll
  for (int c = 0; c < 64; c += 4) {
    v0 = fmaf(s_wva[c * 64 + o],       f1s[w][c],     v0);
    v1 = fmaf(s_wva[(c + 1) * 64 + o], f1s[w][c + 1], v1);
    v2 = fmaf(s_wva[(c + 2) * 64 + o], f1s[w][c + 2], v2);
    v3 = fmaf(s_wva[(c + 3) * 64 + o], f1s[w][c + 3], v3);
  }
  float vb = (v0 + v1) + (v2 + v3);
  float tb = 0.f;
#pragma unroll
  for (int i = 0; i < 16; ++i) {
    int c = part * 16 + i;
    tb = fmaf(s_A2[c * 17 + h], f1s[w][c], tb);
  }
  tb += __shfl_xor(tb, 16);
  tb += __shfl_xor(tb, 32);
  tb -= s_MBP[h];

  float m = -__builtin_inff(), l = 0.f;
  float anb = 0.f, axa = 0.f, aya = 0.f, aza = 0.f;

  if (f2cap) {
    // f32 rows: depth-2 pipeline, step-2 merged softmax
    float4 A0, A1, A2r, A3, B0, B1, B2r, B3;
    float nbAv, nbBv;
    G1_LOADF(A0, A1, A2r, A3, nbAv, idxs[w][0]);
#pragma unroll 1
    for (int s = 0; s < SS; s += 2) {
      G1_LOADF(B0, B1, B2r, B3, nbBv, idxs[w][s + 1]);          // issue s+1 row
      float gl0 = 0.f, dp0 = 0.f;
      dot16f(A0, A1, A2r, A3, Gr, f1r, gl0, dp0);               // consume s row
      float nb0 = nbAv;
      {
        int jn = (s + 2 < SS) ? idxs[w][s + 2] : idxs[w][0];
        G1_LOADF(A0, A1, A2r, A3, nbAv, jn);                    // issue s+2 row
      }
      float gl1 = 0.f, dp1 = 0.f;
      dot16f(B0, B1, B2r, B3, Gr, f1r, gl1, dp1);               // consume s+1 row
      float nb1 = nbBv;
      G1_EPI();
    }
  } else {
    // bf16 rows: same structure
    uint4 UA0, UA1, UB0, UB1;
    uint16_t nbAu, nbBu;
    G1_LOADB(UA0, UA1, nbAu, idxs[w][0]);
#pragma unroll 1
    for (int s = 0; s < SS; s += 2) {
      G1_LOADB(UB0, UB1, nbBu, idxs[w][s + 1]);
      float gl0 = 0.f, dp0 = 0.f;
      dot16b(UA0, UA1, Gr, f1r, gl0, dp0);
      float nb0 = bf2f(nbAu);
      {
        int jn = (s + 2 < SS) ? idxs[w][s + 2] : idxs[w][0];
        G1_LOADB(UA0, UA1, nbAu, jn);
      }
      float gl1 = 0.f, dp1 = 0.f;
      dot16b(UB0, UB1, Gr, f1r, gl1, dp1);
      float nb1 = bf2f(nbBu);
      G1_EPI();
    }
  }

  float invl = 1.f / l;
  anb *= invl; axa *= invl; aya *= invl; aza *= invl;
  float o0 = vb, o1 = 0.f, o2 = 0.f, o3 = 0.f;
#pragma unroll
  for (int c = 0; c < 64; c += 4) {
    o0 = fmaf(s_wvb[c * 64 + o],       __shfl(anb, c),     o0);
    o1 = fmaf(s_wvb[(c + 1) * 64 + o], __shfl(anb, c + 1), o1);
    o2 = fmaf(s_wvb[(c + 2) * 64 + o], __shfl(anb, c + 2), o2);
    o3 = fmaf(s_wvb[(c + 3) * 64 + o], __shfl(anb, c + 3), o3);
  }
  float acc = (o0 + o1) + (o2 + o3);
  acc = fmaf(s_wvx[o], axa, acc);
  acc = fmaf(s_wvx[64 + o], aya, acc);
  acc = fmaf(s_wvx[128 + o], aza, acc);
  float res = acc >= 0.f ? acc : 0.1f * acc;   // leaky 0.1
  ws[off_p2n + (size_t)(b * NN + n) * 64 + o] = res;
}

#define G2_LOAD(A0, A1, A2v, A3, NBV, J) {                              \
      size_t row_ = (size_t)(b * NN + (J)) * 64;                        \
      const float4* r4_ = (const float4*)(p2t + row_) + part * 4;       \
      A0 = r4_[0]; A1 = r4_[1]; A2v = r4_[2]; A3 = r4_[3];              \
      NBV = p2t[row_ + o]; }

// ---------------- group2: per-lane slice loads, depth-2 pipelined gather loop ----------------
__global__ __launch_bounds__(512, 2) void k_group2(
    const void* w_v2, const void* w_pos2, const void* b_pos2,
    u16p probe, float* ws, void* outp, int off_p2n, int off_i11) {
  __shared__ float s_C2[4096];    // [c][o]
  __shared__ float s_wv2[4096];   // [c][o]
  __shared__ float s_wp2t[256];   // [p][o]
  __shared__ float s_bp2[64];
  __shared__ float4 xds4[8][16];
  __shared__ int   idxs[8][16];
  __shared__ float souts[8][64];

  int f32m = detect_f32(probe);
  int tid = threadIdx.x;
  for (int i = tid; i < 4096; i += 512) {
    int c = i >> 6, o = i & 63;
    s_C2[i] = ws[OFF_C2 + i];
    s_wv2[i] = ldi(w_v2, o * 64 + c, f32m);
  }
  if (tid < 256) { int p = tid >> 6, o = tid & 63; s_wp2t[p * 64 + o] = ldi(w_pos2, o * 4 + p, f32m); }
  if (tid < 64) s_bp2[tid] = ldi(b_pos2, tid, f32m);

  int w = tid >> 6, o = tid & 63;
  // XCD-locality remap (r7): same scheme as k_group1 (p2t slice per XCD).
  int blk = blockIdx.x;
  int b = blk & 3, n = ((blk >> 2) << 3) + w;
  const float* p2t = ws + off_p2n;
  const float* x1f = ws + OFF_XYZ1F + b * 3 * NN;
  const uint16_t* idx11 = (const uint16_t*)(ws + off_i11) + (size_t)(b * NN + n) * SS;

  float p1o = p2t[(size_t)(b * NN + n) * 64 + o];
  float qx = x1f[n], qy = x1f[NN + n], qz = x1f[2 * NN + n];
  if (o < 16) {
    int j = (int)idx11[o];
    idxs[w][o] = j;
    float dx = __fsub_rn(qx, x1f[j]);
    float dy = __fsub_rn(qy, x1f[NN + j]);
    float dz = __fsub_rn(qz, x1f[2 * NN + j]);
    xds4[w][o] = make_float4(dx, dy, dz, sqrtf(dx * dx + dy * dy + dz * dz));
  }
  __syncthreads();

  int part = o >> 4;
  // u[o] = (Wk2^T Wq2).pts  via shfl broadcasts of p1o (once per wave)
  float u0 = 0.f, u1 = 0.f, u2 = 0.f, u3 = 0.f;
#pragma unroll
  for (int c = 0; c < 64; c += 4) {
    u0 = fmaf(s_C2[c * 64 + o],       __shfl(p1o, c),     u0);
    u1 = fmaf(s_C2[(c + 1) * 64 + o], __shfl(p1o, c + 1), u1);
    u2 = fmaf(s_C2[(c + 2) * 64 + o], __shfl(p1o, c + 2), u2);
    u3 = fmaf(s_C2[(c + 3) * 64 + o], __shfl(p1o, c + 3), u3);
  }
  float u = (u0 + u1) + (u2 + u3);
  float w4x = u * s_wp2t[o];
  float w4y = u * s_wp2t[64 + o];
  float w4z = u * s_wp2t[128 + o];
  float w4n = u * s_wp2t[192 + o];
  float ubp = u * s_bp2[o];
#pragma unroll
  for (int msk = 1; msk < 64; msk <<= 1) {
    w4x += __shfl_xor(w4x, msk);
    w4y += __shfl_xor(w4y, msk);
    w4z += __shfl_xor(w4z, msk);
    w4n += __shfl_xor(w4n, msk);
    ubp += __shfl_xor(ubp, msk);
  }
  float u16r[16];
#pragma unroll
  for (int i = 0; i < 16; ++i) u16r[i] = __shfl(u, part * 16 + i);

  float m = -__builtin_inff(), l = 0.f, anb = 0.f;
  float4 A0, A1, A2v, A3, B0, B1, B2v, B3;
  float nbAv, nbBv;
  G2_LOAD(A0, A1, A2v, A3, nbAv, idxs[w][0]);
#pragma unroll 1
  for (int s = 0; s < SS; s += 2) {
    G2_LOAD(B0, B1, B2v, B3, nbBv, idxs[w][s + 1]);             // issue s+1 row
    float tp0 = dotu16(A0, A1, A2v, A3, u16r);                  // consume s row
    float nb0 = nbAv;
    {
      int jn = (s + 2 < SS) ? idxs[w][s + 2] : idxs[w][0];
      G2_LOAD(A0, A1, A2v, A3, nbAv, jn);                       // issue s+2 row
    }
    float tp1 = dotu16(B0, B1, B2v, B3, u16r);                  // consume s+1 row
    float nb1 = nbBv;
    tp0 += __shfl_xor(tp0, 16); tp1 += __shfl_xor(tp1, 16);
    tp0 += __shfl_xor(tp0, 32); tp1 += __shfl_xor(tp1, 32);
    float4 xd0 = xds4[w][s], xd1 = xds4[w][s + 1];
    float lg0 = tp0;
    lg0 = fmaf(w4x, xd0.x, lg0);
    lg0 = fmaf(w4y, xd0.y, lg0);
    lg0 = fmaf(w4z, xd0.z, lg0);
    lg0 = fmaf(w4n, xd0.w, lg0);
    lg0 = (lg0 + ubp) * 0.125f;
    float lg1 = tp1;
    lg1 = fmaf(w4x, xd1.x, lg1);
    lg1 = fmaf(w4y, xd1.y, lg1);
    lg1 = fmaf(w4z, xd1.z, lg1);
    lg1 = fmaf(w4n, xd1.w, lg1);
    lg1 = (lg1 + ubp) * 0.125f;
    float mnv = fmaxf(fmaxf(m, lg0), lg1);
    float sc = __expf(m - mnv);
    float e0 = __expf(lg0 - mnv);
    float e1 = __expf(lg1 - mnv);
    l = fmaf(l, sc, e0 + e1);
    anb = fmaf(e1, nb1, fmaf(e0, nb0, anb * sc));
    m = mnv;
  }
  anb *= 1.f / l;
  float o0 = 0.f, o1 = 0.f, o2 = 0.f, o3 = 0.f;
#pragma unroll
  for (int c = 0; c < 64; c += 4) {
    o0 = fmaf(s_wv2[c * 64 + o],       __shfl(anb, c),     o0);
    o1 = fmaf(s_wv2[(c + 1) * 64 + o], __shfl(anb, c + 1), o1);
    o2 = fmaf(s_wv2[(c + 2) * 64 + o], __shfl(anb, c + 2), o2);
    o3 = fmaf(s_wv2[(c + 3) * 64 + o], __shfl(anb, c + 3), o3);
  }
  float acc = (o0 + o1) + (o2 + o3);
  float res = acc >= 0.f ? acc : 0.1f * acc;
  souts[w][o] = res;
  __syncthreads();   // cross-wave transpose staging
  int c = tid >> 3, nr = tid & 7;
  int n0 = (blk >> 2) << 3;   // r7 remap: matches n = n0 + w above
  int b0 = blk & 3;
  size_t oi = (size_t)(b0 * 64 + c) * NN + n0 + nr;
  float ov = souts[nr][c];
  if (f32m) ((float*)outp)[oi] = ov;
  else      ((uint16_t*)outp)[oi] = f2bf(ov);
}

extern "C" void kernel_launch(void* const* d_in, const int* in_sizes, int n_in,
                              void* d_out, int out_size, void* d_ws, size_t ws_size,
                              hipStream_t stream) {
  const void* xyz1 = d_in[0];
  const void* feat1 = d_in[1];
  const void* xyz2 = d_in[2];
  const void* feat2 = d_in[3];
  const void* w_q1 = d_in[4];
  const void* w_k1 = d_in[5];
  const void* w_v1 = d_in[6];
  const void* w_mlp1 = d_in[7];
  const void* w_mlp2 = d_in[8];
  const void* w_pos1 = d_in[9];
  const void* b_pos1 = d_in[10];
  const void* w_q2 = d_in[11];
  const void* w_k2 = d_in[12];
  const void* w_v2 = d_in[13];
  const void* w_pos2 = d_in[14];
  const void* b_pos2 = d_in[15];
  u16p probe = (u16p)d_in[1];
  float* ws = (float*)d_ws;

  if (ws_size < WS_MIN_FLOATS * 4ull) return;

  int big = (ws_size >= 2490368ull * 4ull) ? 1 : 0;
  int f2cap   = big;
  int off_p2n = big ? 1179648 : 655360;
  int off_i12 = big ? 2228224 : 1703936;
  int off_i11 = big ? 2359296 : 1835008;
  int off_aos = off_p2n;   // AoS candidates live in (pre-group1) P2N region

  hipLaunchKernelGGL(k_prep_xyz, dim3(64), dim3(256), 0, stream, xyz1, xyz2, probe, ws, off_aos);
  hipLaunchKernelGGL(k_transpose, dim3(256), dim3(256), 0, stream, feat2, probe, ws, f2cap);
  hipLaunchKernelGGL(k_knn, dim3(8192), dim3(256), 0, stream, ws, off_i12, off_i11, off_aos);
  hipLaunchKernelGGL(k_fold, dim3(66), dim3(256), 0, stream,
                     w_q1, w_k1, w_v1, w_mlp1, w_pos1, b_pos1, w_q2, w_k2, probe, ws, f2cap);
  hipLaunchKernelGGL(k_group1, dim3(2048), dim3(512), 0, stream,
                     feat1, w_v1, w_mlp2, probe, ws, off_p2n, off_i12, f2cap);
  hipLaunchKernelGGL(k_group2, dim3(2048), dim3(512), 0, stream,
                     w_v2, w_pos2, b_pos2, probe, ws, d_out, off_p2n, off_i11);
}

// Round 8
// 491.076 us; speedup vs baseline: 1.0151x; 1.0151x over previous
//
#include <hip/hip_runtime.h>
#include <stdint.h>

#define NN 4096
#define SS 16

// fixed ws float offsets
#define OFF_XYZ1F 0          // 4*3*4096 f32
#define OFF_XYZ2F 49152      // 4*3*4096 f32
#define OFF_N1    98304      // 4*4096 f32 (dead after knn -> nb2 of feat2 points)
#define OFF_N2    114688     // 4*4096 f32 (dead after knn -> folds)
#define OFF_F2T   131072     // feat2 transpose [b][n][c]: u16 (compact) or f32 (big)
#define WS_MIN_FLOATS 1966080ull

// fold outputs (dead-after-knn regions, written by k_fold AFTER k_knn)
#define OFF_NB2 98304    // ||feat2[b][:,n]||^2, 16384 floats (over N1)
#define OFF_A2  114688   // (W1Wq - M*Wva)  [c][h] 1024
#define OFF_G   115712   // (M*Wvb)         [c][h] 1024
#define OFF_P5  116736   // [p][h] 80
#define OFF_MBP 116816   // M*bp1 [h] 16
#define OFF_C2  116832   // Wk2^T*Wq2 [c][o] 4096
// AoS candidate arrays (x,y,z,norm) live in the P2N region: written by k_prep,
// consumed by k_knn, then overwritten by k_group1's P2N output (stream-ordered).
//
// PITFALL (r3-r5 bisect): k_knn's stored distance values are numerics-pinned to
// the reference's near-tie ordering. Caching pass-1 distances for reuse in pass 2
// (a "provably bit-identical" refactor) changed emitted FP code enough to flip a
// near-tie -> wrong neighbor set -> absmax 0.125. DO NOT alter the k_knn distance
// computation/storage path. (Value-level-invariant changes, e.g. reordering a
// fmin reduce over the SAME stored values, are safe: min of a NaN-free multiset
// is bit-identical under any order; exact ties yield +0-consistent patterns.)

typedef const uint16_t* u16p;

__device__ __forceinline__ float bf2f(uint16_t u) {
  return __uint_as_float(((uint32_t)u) << 16);
}
__device__ __forceinline__ uint16_t f2bf(float f) {
  uint32_t x = __float_as_uint(f);
  uint32_t r = (x + 0x7FFFu + ((x >> 16) & 1u)) >> 16;
  return (uint16_t)r;
}
__device__ __forceinline__ float ldi(const void* p, int i, int f32m) {
  return f32m ? ((const float*)p)[i] : bf2f(((const uint16_t*)p)[i]);
}
__device__ __forceinline__ int detect_f32(const uint16_t* probe) {
  int lane = threadIdx.x & 63;
  float a = bf2f(probe[lane]);
  float b = bf2f(probe[lane + 64]);
  int bad = (!(fabsf(a) <= 1e4f)) || (!(fabsf(b) <= 1e4f));
  return __any(bad) ? 1 : 0;
}

// -------- DPP wave-min (VALU-speed; replaces 6-deep ds_swizzle chain) --------
// Canonical GCN wave64 reduction: row_shr 1/2/4/8 (row-local prefix-min, lane 15
// of each row16 holds row min), row_bcast:15 + row_bcast:31 (cross-row combine,
// lane 63 holds full min). bound_ctrl=false + old=src => invalid-source lanes
// keep identity (fmin-safe). Result broadcast via readlane(63).
// Value-level bit-exact vs the shfl_xor butterfly: same multiset, no NaNs.
template <int CTRL>
__device__ __forceinline__ float dpp_fmin(float x) {
  int y = __builtin_amdgcn_update_dpp(__float_as_int(x), __float_as_int(x), CTRL, 0xF, 0xF, false);
  return fminf(x, __int_as_float(y));
}
__device__ __forceinline__ float wave_min_bcast(float x) {
  x = dpp_fmin<0x111>(x);  // row_shr:1
  x = dpp_fmin<0x112>(x);  // row_shr:2
  x = dpp_fmin<0x114>(x);  // row_shr:4
  x = dpp_fmin<0x118>(x);  // row_shr:8
  x = dpp_fmin<0x142>(x);  // row_bcast:15
  x = dpp_fmin<0x143>(x);  // row_bcast:31
  return __int_as_float(__builtin_amdgcn_readlane(__float_as_int(x), 63));
}

// 16-wide dual dot (f32 row regs)
__device__ __forceinline__ void dot16f(const float4& A0, const float4& A1,
                                       const float4& A2r, const float4& A3,
                                       const float* Gr, const float* f1r,
                                       float& gl, float& dp) {
  gl = fmaf(Gr[0], A0.x, gl);   dp = fmaf(f1r[0], A0.x, dp);
  gl = fmaf(Gr[1], A0.y, gl);   dp = fmaf(f1r[1], A0.y, dp);
  gl = fmaf(Gr[2], A0.z, gl);   dp = fmaf(f1r[2], A0.z, dp);
  gl = fmaf(Gr[3], A0.w, gl);   dp = fmaf(f1r[3], A0.w, dp);
  gl = fmaf(Gr[4], A1.x, gl);   dp = fmaf(f1r[4], A1.x, dp);
  gl = fmaf(Gr[5], A1.y, gl);   dp = fmaf(f1r[5], A1.y, dp);
  gl = fmaf(Gr[6], A1.z, gl);   dp = fmaf(f1r[6], A1.z, dp);
  gl = fmaf(Gr[7], A1.w, gl);   dp = fmaf(f1r[7], A1.w, dp);
  gl = fmaf(Gr[8], A2r.x, gl);  dp = fmaf(f1r[8], A2r.x, dp);
  gl = fmaf(Gr[9], A2r.y, gl);  dp = fmaf(f1r[9], A2r.y, dp);
  gl = fmaf(Gr[10], A2r.z, gl); dp = fmaf(f1r[10], A2r.z, dp);
  gl = fmaf(Gr[11], A2r.w, gl); dp = fmaf(f1r[11], A2r.w, dp);
  gl = fmaf(Gr[12], A3.x, gl);  dp = fmaf(f1r[12], A3.x, dp);
  gl = fmaf(Gr[13], A3.y, gl);  dp = fmaf(f1r[13], A3.y, dp);
  gl = fmaf(Gr[14], A3.z, gl);  dp = fmaf(f1r[14], A3.z, dp);
  gl = fmaf(Gr[15], A3.w, gl);  dp = fmaf(f1r[15], A3.w, dp);
}

// 16-wide dual dot (bf16 row regs, unpack on the fly)
__device__ __forceinline__ void dot16b(const uint4& U0, const uint4& U1,
                                       const float* Gr, const float* f1r,
                                       float& gl, float& dp) {
  float nv;
  nv = bf2f((uint16_t)(U0.x & 0xFFFF)); gl = fmaf(Gr[0], nv, gl);  dp = fmaf(f1r[0], nv, dp);
  nv = bf2f((uint16_t)(U0.x >> 16));    gl = fmaf(Gr[1], nv, gl);  dp = fmaf(f1r[1], nv, dp);
  nv = bf2f((uint16_t)(U0.y & 0xFFFF)); gl = fmaf(Gr[2], nv, gl);  dp = fmaf(f1r[2], nv, dp);
  nv = bf2f((uint16_t)(U0.y >> 16));    gl = fmaf(Gr[3], nv, gl);  dp = fmaf(f1r[3], nv, dp);
  nv = bf2f((uint16_t)(U0.z & 0xFFFF)); gl = fmaf(Gr[4], nv, gl);  dp = fmaf(f1r[4], nv, dp);
  nv = bf2f((uint16_t)(U0.z >> 16));    gl = fmaf(Gr[5], nv, gl);  dp = fmaf(f1r[5], nv, dp);
  nv = bf2f((uint16_t)(U0.w & 0xFFFF)); gl = fmaf(Gr[6], nv, gl);  dp = fmaf(f1r[6], nv, dp);
  nv = bf2f((uint16_t)(U0.w >> 16));    gl = fmaf(Gr[7], nv, gl);  dp = fmaf(f1r[7], nv, dp);
  nv = bf2f((uint16_t)(U1.x & 0xFFFF)); gl = fmaf(Gr[8], nv, gl);  dp = fmaf(f1r[8], nv, dp);
  nv = bf2f((uint16_t)(U1.x >> 16));    gl = fmaf(Gr[9], nv, gl);  dp = fmaf(f1r[9], nv, dp);
  nv = bf2f((uint16_t)(U1.y & 0xFFFF)); gl = fmaf(Gr[10], nv, gl); dp = fmaf(f1r[10], nv, dp);
  nv = bf2f((uint16_t)(U1.y >> 16));    gl = fmaf(Gr[11], nv, gl); dp = fmaf(f1r[11], nv, dp);
  nv = bf2f((uint16_t)(U1.z & 0xFFFF)); gl = fmaf(Gr[12], nv, gl); dp = fmaf(f1r[12], nv, dp);
  nv = bf2f((uint16_t)(U1.z >> 16));    gl = fmaf(Gr[13], nv, gl); dp = fmaf(f1r[13], nv, dp);
  nv = bf2f((uint16_t)(U1.w & 0xFFFF)); gl = fmaf(Gr[14], nv, gl); dp = fmaf(f1r[14], nv, dp);
  nv = bf2f((uint16_t)(U1.w >> 16));    gl = fmaf(Gr[15], nv, gl); dp = fmaf(f1r[15], nv, dp);
}

// group2 single dot
__device__ __forceinline__ float dotu16(const float4& A0, const float4& A1,
                                        const float4& A2v, const float4& A3,
                                        const float* u16r) {
  float tp = 0.f;
  tp = fmaf(u16r[0], A0.x, tp);   tp = fmaf(u16r[1], A0.y, tp);
  tp = fmaf(u16r[2], A0.z, tp);   tp = fmaf(u16r[3], A0.w, tp);
  tp = fmaf(u16r[4], A1.x, tp);   tp = fmaf(u16r[5], A1.y, tp);
  tp = fmaf(u16r[6], A1.z, tp);   tp = fmaf(u16r[7], A1.w, tp);
  tp = fmaf(u16r[8], A2v.x, tp);  tp = fmaf(u16r[9], A2v.y, tp);
  tp = fmaf(u16r[10], A2v.z, tp); tp = fmaf(u16r[11], A2v.w, tp);
  tp = fmaf(u16r[12], A3.x, tp);  tp = fmaf(u16r[13], A3.y, tp);
  tp = fmaf(u16r[14], A3.z, tp);  tp = fmaf(u16r[15], A3.w, tp);
  return tp;
}

// ---------------- prep: SoA xyz + norms + AoS candidate float4s ----------------
__global__ __launch_bounds__(256) void k_prep_xyz(const void* xyz1, const void* xyz2,
                                                  u16p probe, float* ws, int off_aos) {
  int f32m = detect_f32(probe);
  int t = blockIdx.x * 256 + threadIdx.x;
  int b = t >> 12, n = t & (NN - 1);
  int base = b * 3 * NN + n;
  float x1 = ldi(xyz1, base, f32m), y1 = ldi(xyz1, base + NN, f32m), z1 = ldi(xyz1, base + 2 * NN, f32m);
  float x2 = ldi(xyz2, base, f32m), y2 = ldi(xyz2, base + NN, f32m), z2 = ldi(xyz2, base + 2 * NN, f32m);
  float* x1f = ws + OFF_XYZ1F;
  float* x2f = ws + OFF_XYZ2F;
  x1f[base] = x1; x1f[base + NN] = y1; x1f[base + 2 * NN] = z1;
  x2f[base] = x2; x2f[base + NN] = y2; x2f[base + 2 * NN] = z2;
  float n1v = __fadd_rn(__fadd_rn(__fmul_rn(x1, x1), __fmul_rn(y1, y1)), __fmul_rn(z1, z1));
  float n2v = __fadd_rn(__fadd_rn(__fmul_rn(x2, x2), __fmul_rn(y2, y2)), __fmul_rn(z2, z2));
  ws[OFF_N1 + t] = n1v;
  ws[OFF_N2 + t] = n2v;
  ((float4*)(ws + off_aos))[t]          = make_float4(x2, y2, z2, n2v);  // which=0 cands
  ((float4*)(ws + off_aos + 65536))[t]  = make_float4(x1, y1, z1, n1v);  // which=1 cands
}

// ---------------- transpose feat2 ----------------
__global__ __launch_bounds__(256) void k_transpose(const void* feat2, u16p probe,
                                                   float* ws, int f2cap) {
  __shared__ float tile[64][65];
  int f32m = detect_f32(probe);
  int b = blockIdx.x >> 6;
  int n0 = (blockIdx.x & 63) * 64;
  int tx = threadIdx.x & 63, ty = threadIdx.x >> 6;
#pragma unroll
  for (int i = 0; i < 16; ++i) {
    int c = i * 4 + ty;
    tile[c][tx] = ldi(feat2, (b * 64 + c) * NN + n0 + tx, f32m);
  }
  __syncthreads();
#pragma unroll
  for (int i = 0; i < 16; ++i) {
    int nl = i * 4 + ty;
    size_t di = (size_t)(b * NN + n0 + nl) * 64 + tx;
    float v = tile[tx][nl];
    if (f2cap) ((float*)(ws + OFF_F2T))[di] = v;
    else       ((uint16_t*)(ws + OFF_F2T))[di] = f2bf(v);
  }
}

// ---------------- KNN: wave-per-query, AoS loads, subsample-threshold ----------------
#define KCAP 320
__device__ __forceinline__ float knn_dist4(float4 cc, float qx, float qy, float qz, float q2) {
  float cross = __fadd_rn(__fadd_rn(__fmul_rn(qx, cc.x), __fmul_rn(qy, cc.y)),
                          __fmul_rn(qz, cc.z));
  return __fsub_rn(__fadd_rn(q2, cc.w), __fmul_rn(2.0f, cross));
}

__global__ __launch_bounds__(256) void k_knn(float* ws, int off_i12, int off_i11, int off_aos) {
  __shared__ float sd[4][KCAP];
  __shared__ int   si[4][KCAP];
  __shared__ int   eqbuf[4][16];

  int tid = threadIdx.x;
  int wv = tid >> 6, lane = tid & 63;
  int q = blockIdx.x * 4 + wv;
  int which = q >> 14;
  int b = (q >> 12) & 3;
  int n = q & (NN - 1);

  const float4* cnd = (const float4*)(ws + off_aos + (which ? 65536 : 0)) + b * NN;
  const float* qp = ws + OFF_XYZ1F + b * 3 * NN;
  float qx = qp[n], qy = qp[NN + n], qz = qp[2 * NN + n];
  float q2 = ws[OFF_N1 + b * NN + n];
  const float INF = __builtin_inff();

  float mn = INF;
#pragma unroll 4
  for (int i = 0; i < 16; ++i) {
    float d = knn_dist4(cnd[i * 64 + lane], qx, qy, qz, q2);
    mn = fminf(mn, d);
  }
  // tau0 = 16th smallest of 64 lane minima via full bitonic sort, take lane 15
  float v = mn;
#pragma unroll
  for (int k = 2; k <= 64; k <<= 1) {
#pragma unroll
    for (int j = k >> 1; j > 0; j >>= 1) {
      float other = __shfl_xor(v, j);
      bool up = ((lane & k) == 0);
      bool lower = ((lane & j) == 0);
      v = (up == lower) ? fminf(v, other) : fmaxf(v, other);
    }
  }
  float tau0 = __shfl(v, 15);

  unsigned long long below = (1ull << lane) - 1ull;
  int c = 0;
#pragma unroll 2
  for (int i = 0; i < 64; ++i) {
    int j = i * 64 + lane;
    float d = knn_dist4(cnd[j], qx, qy, qz, q2);
    bool sel = (d <= tau0);
    unsigned long long msk = __ballot(sel);
    int pos = c + __popcll(msk & below);
    if (sel && pos < KCAP) { sd[wv][pos] = d; si[wv][pos] = j; }
    c += __popcll(msk);
  }
  if (c > KCAP) c = KCAP;   // ~e^-50 event; clamp for safety
  __syncthreads();

  float ch[5];
#pragma unroll
  for (int t = 0; t < 5; ++t) ch[t] = INF;
#pragma unroll
  for (int t = 0; t < 5; ++t) {
    int p = t * 64 + lane;
    float x = (p < c) ? sd[wv][p] : INF;
#pragma unroll
    for (int u = 0; u < 5; ++u) {
      float lo = fminf(ch[u], x);
      x = fmaxf(ch[u], x);
      ch[u] = lo;
    }
  }
  // 16 extraction rounds; wave-min via DPP (r8: value-level bit-exact vs shfl_xor
  // butterfly — same multiset, fmin order-invariant, no NaNs/-0 in distances)
  float tau = 0.f;
  {
    float h = ch[0];
#pragma unroll 1
    for (int r = 0; r < 16; ++r) {
      float ms = wave_min_bcast(h);
      if (r == 15) tau = ms;
      unsigned long long win = __ballot(h == ms);
      int winner = __ffsll(win) - 1;
      if (lane == winner) {
        ch[0] = ch[1]; ch[1] = ch[2]; ch[2] = ch[3]; ch[3] = ch[4]; ch[4] = INF;
        h = ch[0];
      }
    }
  }

  uint16_t* outp = (uint16_t*)(ws + (which ? off_i11 : off_i12)) + (size_t)(b * NN + n) * SS;
  int c1 = 0, eqc = 0;
#pragma unroll
  for (int t = 0; t < 5; ++t) {
    int p = t * 64 + lane;
    bool act = (p < c);
    float d = act ? sd[wv][p] : INF;
    int j = act ? si[wv][p] : 0;
    bool lt = act && (d < tau);
    bool eq = act && (d == tau);
    unsigned long long mlt = __ballot(lt);
    unsigned long long meq = __ballot(eq);
    int pl = __popcll(mlt & below);
    if (lt) outp[c1 + pl] = (uint16_t)j;
    int pe = __popcll(meq & below);
    if (eq && (eqc + pe) < 16) eqbuf[wv][eqc + pe] = j;
    c1 += __popcll(mlt);
    eqc += __popcll(meq);
  }
  __syncthreads();
  int need = 16 - c1;
  if (lane < need) outp[c1 + lane] = (uint16_t)eqbuf[wv][lane];
}

// ---------------- fold: algebraic precomputes + feat2 norms (66 blocks) ----------------
__global__ __launch_bounds__(256) void k_fold(
    const void* w_q1, const void* w_k1, const void* w_v1, const void* w_mlp1,
    const void* w_pos1, const void* b_pos1, const void* w_q2, const void* w_k2,
    u16p probe, float* ws, int f2cap) {
  int f32m = detect_f32(probe);
  int tid = threadIdx.x;

  if (blockIdx.x >= 2) {
    int p = (blockIdx.x - 2) * 256 + tid;
    const float* f2f32 = (const float*)(ws + OFF_F2T);
    const uint16_t* f2u16 = (const uint16_t*)(ws + OFF_F2T);
    size_t row = (size_t)p * 64;
    float acc = 0.f;
#pragma unroll 8
    for (int c = 0; c < 64; ++c) {
      float v = f2cap ? f2f32[row + c] : bf2f(f2u16[row + c]);
      acc = fmaf(v, v, acc);
    }
    ws[OFF_NB2 + p] = acc;
    return;
  }

  __shared__ float lA[4096];
  __shared__ float lB[2048];   // lW1[0:1024], lM[1024:2048]
  if (blockIdx.x == 1) {
    __shared__ float lQ[4096];
    for (int i = tid; i < 4096; i += 256) { lA[i] = ldi(w_k2, i, f32m); lQ[i] = ldi(w_q2, i, f32m); }
    __syncthreads();
    for (int i = tid; i < 4096; i += 256) {
      int c = i >> 6, o = i & 63;
      float a0 = 0.f, a1 = 0.f, a2 = 0.f, a3 = 0.f;
      for (int a = 0; a < 64; a += 4) {
        a0 = fmaf(lA[a * 64 + o],       lQ[a * 64 + c],       a0);
        a1 = fmaf(lA[(a + 1) * 64 + o], lQ[(a + 1) * 64 + c], a1);
        a2 = fmaf(lA[(a + 2) * 64 + o], lQ[(a + 2) * 64 + c], a2);
        a3 = fmaf(lA[(a + 3) * 64 + o], lQ[(a + 3) * 64 + c], a3);
      }
      ws[OFF_C2 + i] = (a0 + a1) + (a2 + a3);
    }
    return;
  }

  float* lW1 = lB;
  float* lM  = lB + 1024;
  for (int i = tid; i < 1024; i += 256) lW1[i] = ldi(w_mlp1, i, f32m);   // [h][m]
  for (int i = tid; i < 4096; i += 256) lA[i] = ldi(w_k1, i, f32m);      // [m][o]
  __syncthreads();
  for (int i = tid; i < 1024; i += 256) {       // M[h][o] = W1.Wk
    int hh = i >> 6, o = i & 63;
    float acc = 0.f;
    for (int m = 0; m < 64; ++m) acc = fmaf(lW1[hh * 64 + m], lA[m * 64 + o], acc);
    lM[i] = acc;
  }
  __syncthreads();
  float a2acc[4];
  for (int i = tid; i < 4096; i += 256) lA[i] = ldi(w_q1, i, f32m);      // [o][c]
  __syncthreads();
  for (int k = 0; k < 4; ++k) {
    int i = tid + k * 256;
    int c = i >> 4, hh = i & 15;
    float acc = 0.f;
    for (int o = 0; o < 64; ++o) acc = fmaf(lW1[hh * 64 + o], lA[o * 64 + c], acc);
    a2acc[k] = acc;
  }
  __syncthreads();
  for (int i = tid; i < 4096; i += 256) { int o = i >> 6, c = i & 63; lA[o * 64 + c] = ldi(w_v1, o * 131 + c, f32m); }
  __syncthreads();
  for (int k = 0; k < 4; ++k) {
    int i = tid + k * 256;
    int c = i >> 4, hh = i & 15;
    float acc = 0.f;
    for (int o = 0; o < 64; ++o) acc = fmaf(lM[hh * 64 + o], lA[o * 64 + c], acc);
    ws[OFF_A2 + i] = a2acc[k] - acc;
  }
  __syncthreads();
  for (int i = tid; i < 4096; i += 256) { int o = i >> 6, c = i & 63; lA[o * 64 + c] = ldi(w_v1, o * 131 + 64 + c, f32m); }
  __syncthreads();
  for (int i = tid; i < 1024; i += 256) {       // G[c][h] = M*Wvb
    int c = i >> 4, hh = i & 15;
    float acc = 0.f;
    for (int o = 0; o < 64; ++o) acc = fmaf(lM[hh * 64 + o], lA[o * 64 + c], acc);
    ws[OFF_G + i] = acc;
  }
  if (tid < 16) {
    int hh = tid;
    float p0 = 0.f, p1 = 0.f, p2 = 0.f, p3 = 0.f, p4 = 0.f, pb = 0.f;
    for (int o = 0; o < 64; ++o) {
      float m = lM[hh * 64 + o];
      p0 = fmaf(m, ldi(w_pos1, o * 5 + 0, f32m), p0);
      p1 = fmaf(m, ldi(w_pos1, o * 5 + 1, f32m), p1);
      p2 = fmaf(m, ldi(w_v1, o * 131 + 128, f32m) + ldi(w_pos1, o * 5 + 2, f32m), p2);
      p3 = fmaf(m, ldi(w_v1, o * 131 + 129, f32m) + ldi(w_pos1, o * 5 + 3, f32m), p3);
      p4 = fmaf(m, ldi(w_v1, o * 131 + 130, f32m) + ldi(w_pos1, o * 5 + 4, f32m), p4);
      pb = fmaf(m, ldi(b_pos1, o, f32m), pb);
    }
    ws[OFF_P5 + hh] = p0; ws[OFF_P5 + 16 + hh] = p1; ws[OFF_P5 + 32 + hh] = p2;
    ws[OFF_P5 + 48 + hh] = p3; ws[OFF_P5 + 64 + hh] = p4;
    ws[OFF_MBP + hh] = pb;
  }
}

// shared dual-step online-softmax epilogue for group1's s-loop.
// Consumes gl0,dp0,nb0 (step s) and gl1,dp1,nb1 (step s+1); updates m,l,anb,axa,aya,aza.
#define G1_EPI()                                                        \
      gl0 += __shfl_xor(gl0, 16); dp0 += __shfl_xor(dp0, 16);           \
      gl1 += __shfl_xor(gl1, 16); dp1 += __shfl_xor(dp1, 16);           \
      gl0 += __shfl_xor(gl0, 32); dp0 += __shfl_xor(dp0, 32);           \
      gl1 += __shfl_xor(gl1, 32); dp1 += __shfl_xor(dp1, 32);           \
      float4 xd0 = xds4[w][s];                                          \
      float4 xd1 = xds4[w][s + 1];                                      \
      float fn0 = sqrtf(fmaxf(f1n2 - 2.f * dp0 + snb2[w][s], 0.f));     \
      float fn1 = sqrtf(fmaxf(f1n2 - 2.f * dp1 + snb2[w][s + 1], 0.f)); \
      float p50 = p5a * fn0;                                            \
      p50 = fmaf(p5b, xd0.w, p50); p50 = fmaf(p5c, xd0.x, p50);         \
      p50 = fmaf(p5d, xd0.y, p50); p50 = fmaf(p5e, xd0.z, p50);         \
      float p51 = p5a * fn1;                                            \
      p51 = fmaf(p5b, xd1.w, p51); p51 = fmaf(p5c, xd1.x, p51);         \
      p51 = fmaf(p5d, xd1.y, p51); p51 = fmaf(p5e, xd1.z, p51);         \
      float r0 = fmaxf(tb - gl0 - p50, 0.f) * w2r;                      \
      float r1 = fmaxf(tb - gl1 - p51, 0.f) * w2r;                      \
      r0 += __shfl_xor(r0, 1); r1 += __shfl_xor(r1, 1);                 \
      r0 += __shfl_xor(r0, 2); r1 += __shfl_xor(r1, 2);                 \
      r0 += __shfl_xor(r0, 4); r1 += __shfl_xor(r1, 4);                 \
      r0 += __shfl_xor(r0, 8); r1 += __shfl_xor(r1, 8);                 \
      float mnv = fmaxf(fmaxf(m, r0), r1);                              \
      float sc = __expf(m - mnv);                                       \
      float e0 = __expf(r0 - mnv);                                      \
      float e1 = __expf(r1 - mnv);                                      \
      l = fmaf(l, sc, e0 + e1);                                         \
      anb = fmaf(e1, nb1, fmaf(e0, nb0, anb * sc));                     \
      axa = fmaf(e1, xd1.x, fmaf(e0, xd0.x, axa * sc));                 \
      aya = fmaf(e1, xd1.y, fmaf(e0, xd0.y, aya * sc));                 \
      aza = fmaf(e1, xd1.z, fmaf(e0, xd0.z, aza * sc));                 \
      m = mnv;

#define G1_LOADF(A0, A1, A2r, A3, NBV, J) {                             \
      size_t row_ = (size_t)(b * NN + (J)) * 64;                        \
      const float4* r4_ = (const float4*)(f2f32 + row_) + part * 4;     \
      A0 = r4_[0]; A1 = r4_[1]; A2r = r4_[2]; A3 = r4_[3];              \
      NBV = f2f32[row_ + o]; }

#define G1_LOADB(U0, U1, NBU, J) {                                      \
      size_t row_ = (size_t)(b * NN + (J)) * 64;                        \
      const uint4* r4_ = (const uint4*)(f2u16 + row_) + part * 2;       \
      U0 = r4_[0]; U1 = r4_[1]; NBU = f2u16[row_ + o]; }

// ---------------- group1: per-lane slice loads, depth-2 pipelined gather loop ----------------
// launch_bounds (512,2): 2 BLOCKS/CU (CUDA semantics, r8 post-mortem) => 128-VGPR cap.
__global__ __launch_bounds__(512, 2) void k_group1(
    const void* feat1, const void* w_v1, const void* w_mlp2,
    u16p probe, float* ws, int off_p2n, int off_i12, int f2cap) {
  __shared__ float s_wva[4096];    // [c][o]
  __shared__ float s_wvb[4096];    // [c][o]
  __shared__ float s_wvx[192];
  __shared__ float s_A2[1088];     // [c*17+h] padded
  __shared__ float s_G[1088];      // [c*17+h] padded
  __shared__ float s_P5[80];
  __shared__ float s_MBP[16];
  __shared__ float s_w2[16];
  __shared__ float f1s[8][64];
  __shared__ float4 xds4[8][16];   // per s: (dx,dy,dz,norm)
  __shared__ float snb2[8][16];
  __shared__ int   idxs[8][16];

  int f32m = detect_f32(probe);
  int tid = threadIdx.x;
  for (int i = tid; i < 4096; i += 512) {
    int c = i >> 6, o = i & 63;
    s_wva[i] = ldi(w_v1, o * 131 + c, f32m);
    s_wvb[i] = ldi(w_v1, o * 131 + 64 + c, f32m);
  }
  if (tid < 192) { int j = tid >> 6, o = tid & 63; s_wvx[tid] = ldi(w_v1, o * 131 + 128 + j, f32m); }
  for (int i = tid; i < 1024; i += 512) {
    int c = i >> 4, h = i & 15;
    s_A2[c * 17 + h] = ws[OFF_A2 + i];
    s_G[c * 17 + h] = ws[OFF_G + i];
  }
  if (tid < 80) s_P5[tid] = ws[OFF_P5 + tid];
  if (tid < 16) { s_MBP[tid] = ws[OFF_MBP + tid]; s_w2[tid] = ldi(w_mlp2, tid, f32m); }

  int w = tid >> 6, o = tid & 63;
  int g = blockIdx.x * 8 + w;
  int b = g >> 12, n = g & (NN - 1);
  const float* x1f = ws + OFF_XYZ1F + b * 3 * NN;
  const float* x2f = ws + OFF_XYZ2F + b * 3 * NN;
  const uint16_t* idx12 = (const uint16_t*)(ws + off_i12) + (size_t)(b * NN + n) * SS;
  const float* f2f32 = (const float*)(ws + OFF_F2T);
  const uint16_t* f2u16 = (const uint16_t*)(ws + OFF_F2T);

  float f1o = ldi(feat1, (b * 64 + o) * NN + n, f32m);
  f1s[w][o] = f1o;
  float qx = x1f[n], qy = x1f[NN + n], qz = x1f[2 * NN + n];
  if (o < 16) {
    int j = (int)idx12[o];
    idxs[w][o] = j;
    float dx = __fsub_rn(qx, x2f[j]);
    float dy = __fsub_rn(qy, x2f[NN + j]);
    float dz = __fsub_rn(qz, x2f[2 * NN + j]);
    xds4[w][o] = make_float4(dx, dy, dz, sqrtf(dx * dx + dy * dy + dz * dz));
    snb2[w][o] = ws[OFF_NB2 + b * NN + j];
  }
  __syncthreads();   // only block barrier; below: regs/shfl/read-only LDS

  int h = o & 15, part = o >> 4;
  float Gr[16], f1r[16];
#pragma unroll
  for (int i = 0; i < 16; ++i) {
    int c = part * 16 + i;
    Gr[i] = s_G[c * 17 + h];
    f1r[i] = f1s[w][c];
  }
  float p5a = s_P5[h], p5b = s_P5[16 + h], p5c = s_P5[32 + h], p5d = s_P5[48 + h], p5e = s_P5[64 + h];
  float w2r = s_w2[h];

  float f1n2 = f1o * f1o;
#pragma unroll
  for (int msk = 1; msk < 64; msk <<= 1) f1n2 += __shfl_xor(f1n2, msk);
  float v0 = 0.f, v1 = 0.f, v2 = 0.f, v3 = 0.f;
#pragma unroll
  for (int c = 0; c < 64; c += 4) {
    v0 = fmaf(s_wva[c * 64 + o],       f1s[w][c],     v0);
    v1 = fmaf(s_wva[(c + 1) * 64 + o], f1s[w][c + 1], v1);
    v2 = fmaf(s_wva[(c + 2) * 64 + o], f1s[w][c + 2], v2);
    v3 = fmaf(s_wva[(c + 3) * 64 + o], f1s[w][c + 3], v3);
  }
  float vb = (v0 + v1) + (v2 + v3);
  float tb = 0.f;
#pragma unroll
  for (int i = 0; i < 16; ++i) {
    int c = part * 16 + i;
    tb = fmaf(s_A2[c * 17 + h], f1s[w][c], tb);
  }
  tb += __shfl_xor(tb, 16);
  tb += __shfl_xor(tb, 32);
  tb -= s_MBP[h];

  float m = -__builtin_inff(), l = 0.f;
  float anb = 0.f, axa = 0.f, aya = 0.f, aza = 0.f;

  if (f2cap) {
    // f32 rows: depth-2 pipeline, step-2 merged softmax
    float4 A0, A1, A2r, A3, B0, B1, B2r, B3;
    float nbAv, nbBv;
    G1_LOADF(A0, A1, A2r, A3, nbAv, idxs[w][0]);
#pragma unroll 1
    for (int s = 0; s < SS; s += 2) {
      G1_LOADF(B0, B1, B2r, B3, nbBv, idxs[w][s + 1]);          // issue s+1 row
      float gl0 = 0.f, dp0 = 0.f;
      dot16f(A0, A1, A2r, A3, Gr, f1r, gl0, dp0);               // consume s row
      float nb0 = nbAv;
      {
        int jn = (s + 2 < SS) ? idxs[w][s + 2] : idxs[w][0];
        G1_LOADF(A0, A1, A2r, A3, nbAv, jn);                    // issue s+2 row
      }
      float gl1 = 0.f, dp1 = 0.f;
      dot16f(B0, B1, B2r, B3, Gr, f1r, gl1, dp1);               // consume s+1 row
      float nb1 = nbBv;
      G1_EPI();
    }
  } else {
    // bf16 rows: same structure
    uint4 UA0, UA1, UB0, UB1;
    uint16_t nbAu, nbBu;
    G1_LOADB(UA0, UA1, nbAu, idxs[w][0]);
#pragma unroll 1
    for (int s = 0; s < SS; s += 2) {
      G1_LOADB(UB0, UB1, nbBu, idxs[w][s + 1]);
      float gl0 = 0.f, dp0 = 0.f;
      dot16b(UA0, UA1, Gr, f1r, gl0, dp0);
      float nb0 = bf2f(nbAu);
      {
        int jn = (s + 2 < SS) ? idxs[w][s + 2] : idxs[w][0];
        G1_LOADB(UA0, UA1, nbAu, jn);
      }
      float gl1 = 0.f, dp1 = 0.f;
      dot16b(UB0, UB1, Gr, f1r, gl1, dp1);
      float nb1 = bf2f(nbBu);
      G1_EPI();
    }
  }

  float invl = 1.f / l;
  anb *= invl; axa *= invl; aya *= invl; aza *= invl;
  float o0 = vb, o1 = 0.f, o2 = 0.f, o3 = 0.f;
#pragma unroll
  for (int c = 0; c < 64; c += 4) {
    o0 = fmaf(s_wvb[c * 64 + o],       __shfl(anb, c),     o0);
    o1 = fmaf(s_wvb[(c + 1) * 64 + o], __shfl(anb, c + 1), o1);
    o2 = fmaf(s_wvb[(c + 2) * 64 + o], __shfl(anb, c + 2), o2);
    o3 = fmaf(s_wvb[(c + 3) * 64 + o], __shfl(anb, c + 3), o3);
  }
  float acc = (o0 + o1) + (o2 + o3);
  acc = fmaf(s_wvx[o], axa, acc);
  acc = fmaf(s_wvx[64 + o], aya, acc);
  acc = fmaf(s_wvx[128 + o], aza, acc);
  float res = acc >= 0.f ? acc : 0.1f * acc;   // leaky 0.1
  ws[off_p2n + (size_t)(b * NN + n) * 64 + o] = res;
}

#define G2_LOAD(A0, A1, A2v, A3, NBV, J) {                              \
      size_t row_ = (size_t)(b * NN + (J)) * 64;                        \
      const float4* r4_ = (const float4*)(p2t + row_) + part * 4;       \
      A0 = r4_[0]; A1 = r4_[1]; A2v = r4_[2]; A3 = r4_[3];              \
      NBV = p2t[row_ + o]; }

// ---------------- group2: per-lane slice loads, depth-2 pipelined gather loop ----------------
__global__ __launch_bounds__(512, 2) void k_group2(
    const void* w_v2, const void* w_pos2, const void* b_pos2,
    u16p probe, float* ws, void* outp, int off_p2n, int off_i11) {
  __shared__ float s_C2[4096];    // [c][o]
  __shared__ float s_wv2[4096];   // [c][o]
  __shared__ float s_wp2t[256];   // [p][o]
  __shared__ float s_bp2[64];
  __shared__ float4 xds4[8][16];
  __shared__ int   idxs[8][16];
  __shared__ float souts[8][64];

  int f32m = detect_f32(probe);
  int tid = threadIdx.x;
  for (int i = tid; i < 4096; i += 512) {
    int c = i >> 6, o = i & 63;
    s_C2[i] = ws[OFF_C2 + i];
    s_wv2[i] = ldi(w_v2, o * 64 + c, f32m);
  }
  if (tid < 256) { int p = tid >> 6, o = tid & 63; s_wp2t[p * 64 + o] = ldi(w_pos2, o * 4 + p, f32m); }
  if (tid < 64) s_bp2[tid] = ldi(b_pos2, tid, f32m);

  int w = tid >> 6, o = tid & 63;
  int g = blockIdx.x * 8 + w;
  int b = g >> 12, n = g & (NN - 1);
  const float* p2t = ws + off_p2n;
  const float* x1f = ws + OFF_XYZ1F + b * 3 * NN;
  const uint16_t* idx11 = (const uint16_t*)(ws + off_i11) + (size_t)(b * NN + n) * SS;

  float p1o = p2t[(size_t)(b * NN + n) * 64 + o];
  float qx = x1f[n], qy = x1f[NN + n], qz = x1f[2 * NN + n];
  if (o < 16) {
    int j = (int)idx11[o];
    idxs[w][o] = j;
    float dx = __fsub_rn(qx, x1f[j]);
    float dy = __fsub_rn(qy, x1f[NN + j]);
    float dz = __fsub_rn(qz, x1f[2 * NN + j]);
    xds4[w][o] = make_float4(dx, dy, dz, sqrtf(dx * dx + dy * dy + dz * dz));
  }
  __syncthreads();

  int part = o >> 4;
  // u[o] = (Wk2^T Wq2).pts  via shfl broadcasts of p1o (once per wave)
  float u0 = 0.f, u1 = 0.f, u2 = 0.f, u3 = 0.f;
#pragma unroll
  for (int c = 0; c < 64; c += 4) {
    u0 = fmaf(s_C2[c * 64 + o],       __shfl(p1o, c),     u0);
    u1 = fmaf(s_C2[(c + 1) * 64 + o], __shfl(p1o, c + 1), u1);
    u2 = fmaf(s_C2[(c + 2) * 64 + o], __shfl(p1o, c + 2), u2);
    u3 = fmaf(s_C2[(c + 3) * 64 + o], __shfl(p1o, c + 3), u3);
  }
  float u = (u0 + u1) + (u2 + u3);
  float w4x = u * s_wp2t[o];
  float w4y = u * s_wp2t[64 + o];
  float w4z = u * s_wp2t[128 + o];
  float w4n = u * s_wp2t[192 + o];
  float ubp = u * s_bp2[o];
#pragma unroll
  for (int msk = 1; msk < 64; msk <<= 1) {
    w4x += __shfl_xor(w4x, msk);
    w4y += __shfl_xor(w4y, msk);
    w4z += __shfl_xor(w4z, msk);
    w4n += __shfl_xor(w4n, msk);
    ubp += __shfl_xor(ubp, msk);
  }
  float u16r[16];
#pragma unroll
  for (int i = 0; i < 16; ++i) u16r[i] = __shfl(u, part * 16 + i);

  float m = -__builtin_inff(), l = 0.f, anb = 0.f;
  float4 A0, A1, A2v, A3, B0, B1, B2v, B3;
  float nbAv, nbBv;
  G2_LOAD(A0, A1, A2v, A3, nbAv, idxs[w][0]);
#pragma unroll 1
  for (int s = 0; s < SS; s += 2) {
    G2_LOAD(B0, B1, B2v, B3, nbBv, idxs[w][s + 1]);             // issue s+1 row
    float tp0 = dotu16(A0, A1, A2v, A3, u16r);                  // consume s row
    float nb0 = nbAv;
    {
      int jn = (s + 2 < SS) ? idxs[w][s + 2] : idxs[w][0];
      G2_LOAD(A0, A1, A2v, A3, nbAv, jn);                       // issue s+2 row
    }
    float tp1 = dotu16(B0, B1, B2v, B3, u16r);                  // consume s+1 row
    float nb1 = nbBv;
    tp0 += __shfl_xor(tp0, 16); tp1 += __shfl_xor(tp1, 16);
    tp0 += __shfl_xor(tp0, 32); tp1 += __shfl_xor(tp1, 32);
    float4 xd0 = xds4[w][s], xd1 = xds4[w][s + 1];
    float lg0 = tp0;
    lg0 = fmaf(w4x, xd0.x, lg0);
    lg0 = fmaf(w4y, xd0.y, lg0);
    lg0 = fmaf(w4z, xd0.z, lg0);
    lg0 = fmaf(w4n, xd0.w, lg0);
    lg0 = (lg0 + ubp) * 0.125f;
    float lg1 = tp1;
    lg1 = fmaf(w4x, xd1.x, lg1);
    lg1 = fmaf(w4y, xd1.y, lg1);
    lg1 = fmaf(w4z, xd1.z, lg1);
    lg1 = fmaf(w4n, xd1.w, lg1);
    lg1 = (lg1 + ubp) * 0.125f;
    float mnv = fmaxf(fmaxf(m, lg0), lg1);
    float sc = __expf(m - mnv);
    float e0 = __expf(lg0 - mnv);
    float e1 = __expf(lg1 - mnv);
    l = fmaf(l, sc, e0 + e1);
    anb = fmaf(e1, nb1, fmaf(e0, nb0, anb * sc));
    m = mnv;
  }
  anb *= 1.f / l;
  float o0 = 0.f, o1 = 0.f, o2 = 0.f, o3 = 0.f;
#pragma unroll
  for (int c = 0; c < 64; c += 4) {
    o0 = fmaf(s_wv2[c * 64 + o],       __shfl(anb, c),     o0);
    o1 = fmaf(s_wv2[(c + 1) * 64 + o], __shfl(anb, c + 1), o1);
    o2 = fmaf(s_wv2[(c + 2) * 64 + o], __shfl(anb, c + 2), o2);
    o3 = fmaf(s_wv2[(c + 3) * 64 + o], __shfl(anb, c + 3), o3);
  }
  float acc = (o0 + o1) + (o2 + o3);
  float res = acc >= 0.f ? acc : 0.1f * acc;
  souts[w][o] = res;
  __syncthreads();   // cross-wave transpose staging
  int c = tid >> 3, nr = tid & 7;
  int n0 = (blockIdx.x * 8) & (NN - 1);
  int b0 = (blockIdx.x * 8) >> 12;
  size_t oi = (size_t)(b0 * 64 + c) * NN + n0 + nr;
  float ov = souts[nr][c];
  if (f32m) ((float*)outp)[oi] = ov;
  else      ((uint16_t*)outp)[oi] = f2bf(ov);
}

extern "C" void kernel_launch(void* const* d_in, const int* in_sizes, int n_in,
                              void* d_out, int out_size, void* d_ws, size_t ws_size,
                              hipStream_t stream) {
  const void* xyz1 = d_in[0];
  const void* feat1 = d_in[1];
  const void* xyz2 = d_in[2];
  const void* feat2 = d_in[3];
  const void* w_q1 = d_in[4];
  const void* w_k1 = d_in[5];
  const void* w_v1 = d_in[6];
  const void* w_mlp1 = d_in[7];
  const void* w_mlp2 = d_in[8];
  const void* w_pos1 = d_in[9];
  const void* b_pos1 = d_in[10];
  const void* w_q2 = d_in[11];
  const void* w_k2 = d_in[12];
  const void* w_v2 = d_in[13];
  const void* w_pos2 = d_in[14];
  const void* b_pos2 = d_in[15];
  u16p probe = (u16p)d_in[1];
  float* ws = (float*)d_ws;

  if (ws_size < WS_MIN_FLOATS * 4ull) return;

  int big = (ws_size >= 2490368ull * 4ull) ? 1 : 0;
  int f2cap   = big;
  int off_p2n = big ? 1179648 : 655360;
  int off_i12 = big ? 2228224 : 1703936;
  int off_i11 = big ? 2359296 : 1835008;
  int off_aos = off_p2n;   // AoS candidates live in (pre-group1) P2N region

  hipLaunchKernelGGL(k_prep_xyz, dim3(64), dim3(256), 0, stream, xyz1, xyz2, probe, ws, off_aos);
  hipLaunchKernelGGL(k_transpose, dim3(256), dim3(256), 0, stream, feat2, probe, ws, f2cap);
  hipLaunchKernelGGL(k_knn, dim3(8192), dim3(256), 0, stream, ws, off_i12, off_i11, off_aos);
  hipLaunchKernelGGL(k_fold, dim3(66), dim3(256), 0, stream,
                     w_q1, w_k1, w_v1, w_mlp1, w_pos1, b_pos1, w_q2, w_k2, probe, ws, f2cap);
  hipLaunchKernelGGL(k_group1, dim3(2048), dim3(512), 0, stream,
                     feat1, w_v1, w_mlp2, probe, ws, off_p2n, off_i12, f2cap);
  hipLaunchKernelGGL(k_group2, dim3(2048), dim3(512), 0, stream,
                     w_v2, w_pos2, b_pos2, probe, ws, d_out, off_p2n, off_i11);
}

// Round 9
// 490.048 us; speedup vs baseline: 1.0172x; 1.0021x over previous
//
#include <hip/hip_runtime.h>
#include <stdint.h>

#define NN 4096
#define SS 16

// fixed ws float offsets
#define OFF_XYZ1F 0          // 4*3*4096 f32
#define OFF_XYZ2F 49152      // 4*3*4096 f32
#define OFF_N1    98304      // 4*4096 f32 (dead after knn -> nb2 of feat2 points)
#define OFF_N2    114688     // 4*4096 f32 (dead after knn -> folds)
#define OFF_F2T   131072     // feat2 transpose [b][n][c]: u16 (compact) or f32 (big)
#define WS_MIN_FLOATS 1966080ull

// fold outputs (dead-after-knn regions, written by k_fold AFTER k_knn)
#define OFF_NB2 98304    // ||feat2[b][:,n]||^2, 16384 floats (over N1)
#define OFF_A2  114688   // (W1Wq - M*Wva)  [c][h] 1024
#define OFF_G   115712   // (M*Wvb)         [c][h] 1024
#define OFF_P5  116736   // [p][h] 80
#define OFF_MBP 116816   // M*bp1 [h] 16
#define OFF_C2  116832   // Wk2^T*Wq2 [c][o] 4096
// AoS candidate arrays (x,y,z,norm) live in the P2N region: written by k_prep,
// consumed by k_knn, then overwritten by k_group1's P2N output (stream-ordered).
//
// PITFALL (r3-r5 bisect): k_knn's stored distance values are numerics-pinned to
// the reference's near-tie ordering. Caching pass-1 distances for reuse in pass 2
// (a "provably bit-identical" refactor) changed emitted FP code enough to flip a
// near-tie -> wrong neighbor set -> absmax 0.125. DO NOT alter the k_knn distance
// computation/storage path. (Value-level-invariant changes, e.g. reordering a
// fmin reduce over the SAME stored values, are safe: min of a NaN-free multiset
// is bit-identical under any order; exact ties yield +0-consistent patterns.)
//
// r8 verified: DPP wave-min in k_knn extraction = WIN (k_knn 136->133us, VALU 82->96%).
// k_knn is now VALU-throughput-bound with a frozen distance path: no further lever.

typedef const uint16_t* u16p;

__device__ __forceinline__ float bf2f(uint16_t u) {
  return __uint_as_float(((uint32_t)u) << 16);
}
__device__ __forceinline__ uint16_t f2bf(float f) {
  uint32_t x = __float_as_uint(f);
  uint32_t r = (x + 0x7FFFu + ((x >> 16) & 1u)) >> 16;
  return (uint16_t)r;
}
__device__ __forceinline__ float ldi(const void* p, int i, int f32m) {
  return f32m ? ((const float*)p)[i] : bf2f(((const uint16_t*)p)[i]);
}
__device__ __forceinline__ int detect_f32(const uint16_t* probe) {
  int lane = threadIdx.x & 63;
  float a = bf2f(probe[lane]);
  float b = bf2f(probe[lane + 64]);
  int bad = (!(fabsf(a) <= 1e4f)) || (!(fabsf(b) <= 1e4f));
  return __any(bad) ? 1 : 0;
}

// -------- DPP helpers --------
template <int CTRL>
__device__ __forceinline__ float dpp_fmin(float x) {
  int y = __builtin_amdgcn_update_dpp(__float_as_int(x), __float_as_int(x), CTRL, 0xF, 0xF, false);
  return fminf(x, __int_as_float(y));
}
template <int CTRL>
__device__ __forceinline__ float dpp_fadd(float x) {
  int y = __builtin_amdgcn_update_dpp(__float_as_int(x), __float_as_int(x), CTRL, 0xF, 0xF, false);
  return x + __int_as_float(y);
}
// wave64 min -> broadcast (k_knn extraction; r8-verified on HW)
__device__ __forceinline__ float wave_min_bcast(float x) {
  x = dpp_fmin<0x111>(x);  // row_shr:1
  x = dpp_fmin<0x112>(x);  // row_shr:2
  x = dpp_fmin<0x114>(x);  // row_shr:4
  x = dpp_fmin<0x118>(x);  // row_shr:8
  x = dpp_fmin<0x142>(x);  // row_bcast:15
  x = dpp_fmin<0x143>(x);  // row_bcast:31
  return __int_as_float(__builtin_amdgcn_readlane(__float_as_int(x), 63));
}
// within-16-lane sum reduce, BIT-IDENTICAL to the xor1/2/4/8 shfl butterfly:
// stage1 quad_perm(1,0,3,2)=0xB1 == xor1; stage2 quad_perm(2,3,0,1)=0x4E == xor2;
// stage3 row_half_mirror=0x141: partner i^7 is in the SAME quad as i^4, and after
// stages 1-2 every lane of a quad holds the identical quad-sum => same addend as
// xor4; stage4 row_mirror=0x140: partner i^15 in same 8-group as i^8 => same
// addend as xor8. Same values, same order => bit-identical result.
__device__ __forceinline__ float sum16_dpp(float x) {
  x = dpp_fadd<0xB1>(x);   // xor1
  x = dpp_fadd<0x4E>(x);   // xor2
  x = dpp_fadd<0x141>(x);  // row_half_mirror (== xor4 addend)
  x = dpp_fadd<0x140>(x);  // row_mirror      (== xor8 addend)
  return x;
}

// 16-wide dual dot (f32 row regs)
__device__ __forceinline__ void dot16f(const float4& A0, const float4& A1,
                                       const float4& A2r, const float4& A3,
                                       const float* Gr, const float* f1r,
                                       float& gl, float& dp) {
  gl = fmaf(Gr[0], A0.x, gl);   dp = fmaf(f1r[0], A0.x, dp);
  gl = fmaf(Gr[1], A0.y, gl);   dp = fmaf(f1r[1], A0.y, dp);
  gl = fmaf(Gr[2], A0.z, gl);   dp = fmaf(f1r[2], A0.z, dp);
  gl = fmaf(Gr[3], A0.w, gl);   dp = fmaf(f1r[3], A0.w, dp);
  gl = fmaf(Gr[4], A1.x, gl);   dp = fmaf(f1r[4], A1.x, dp);
  gl = fmaf(Gr[5], A1.y, gl);   dp = fmaf(f1r[5], A1.y, dp);
  gl = fmaf(Gr[6], A1.z, gl);   dp = fmaf(f1r[6], A1.z, dp);
  gl = fmaf(Gr[7], A1.w, gl);   dp = fmaf(f1r[7], A1.w, dp);
  gl = fmaf(Gr[8], A2r.x, gl);  dp = fmaf(f1r[8], A2r.x, dp);
  gl = fmaf(Gr[9], A2r.y, gl);  dp = fmaf(f1r[9], A2r.y, dp);
  gl = fmaf(Gr[10], A2r.z, gl); dp = fmaf(f1r[10], A2r.z, dp);
  gl = fmaf(Gr[11], A2r.w, gl); dp = fmaf(f1r[11], A2r.w, dp);
  gl = fmaf(Gr[12], A3.x, gl);  dp = fmaf(f1r[12], A3.x, dp);
  gl = fmaf(Gr[13], A3.y, gl);  dp = fmaf(f1r[13], A3.y, dp);
  gl = fmaf(Gr[14], A3.z, gl);  dp = fmaf(f1r[14], A3.z, dp);
  gl = fmaf(Gr[15], A3.w, gl);  dp = fmaf(f1r[15], A3.w, dp);
}

// 16-wide dual dot (bf16 row regs, unpack on the fly)
__device__ __forceinline__ void dot16b(const uint4& U0, const uint4& U1,
                                       const float* Gr, const float* f1r,
                                       float& gl, float& dp) {
  float nv;
  nv = bf2f((uint16_t)(U0.x & 0xFFFF)); gl = fmaf(Gr[0], nv, gl);  dp = fmaf(f1r[0], nv, dp);
  nv = bf2f((uint16_t)(U0.x >> 16));    gl = fmaf(Gr[1], nv, gl);  dp = fmaf(f1r[1], nv, dp);
  nv = bf2f((uint16_t)(U0.y & 0xFFFF)); gl = fmaf(Gr[2], nv, gl);  dp = fmaf(f1r[2], nv, dp);
  nv = bf2f((uint16_t)(U0.y >> 16));    gl = fmaf(Gr[3], nv, gl);  dp = fmaf(f1r[3], nv, dp);
  nv = bf2f((uint16_t)(U0.z & 0xFFFF)); gl = fmaf(Gr[4], nv, gl);  dp = fmaf(f1r[4], nv, dp);
  nv = bf2f((uint16_t)(U0.z >> 16));    gl = fmaf(Gr[5], nv, gl);  dp = fmaf(f1r[5], nv, dp);
  nv = bf2f((uint16_t)(U0.w & 0xFFFF)); gl = fmaf(Gr[6], nv, gl);  dp = fmaf(f1r[6], nv, dp);
  nv = bf2f((uint16_t)(U0.w >> 16));    gl = fmaf(Gr[7], nv, gl);  dp = fmaf(f1r[7], nv, dp);
  nv = bf2f((uint16_t)(U1.x & 0xFFFF)); gl = fmaf(Gr[8], nv, gl);  dp = fmaf(f1r[8], nv, dp);
  nv = bf2f((uint16_t)(U1.x >> 16));    gl = fmaf(Gr[9], nv, gl);  dp = fmaf(f1r[9], nv, dp);
  nv = bf2f((uint16_t)(U1.y & 0xFFFF)); gl = fmaf(Gr[10], nv, gl); dp = fmaf(f1r[10], nv, dp);
  nv = bf2f((uint16_t)(U1.y >> 16));    gl = fmaf(Gr[11], nv, gl); dp = fmaf(f1r[11], nv, dp);
  nv = bf2f((uint16_t)(U1.z & 0xFFFF)); gl = fmaf(Gr[12], nv, gl); dp = fmaf(f1r[12], nv, dp);
  nv = bf2f((uint16_t)(U1.z >> 16));    gl = fmaf(Gr[13], nv, gl); dp = fmaf(f1r[13], nv, dp);
  nv = bf2f((uint16_t)(U1.w & 0xFFFF)); gl = fmaf(Gr[14], nv, gl); dp = fmaf(f1r[14], nv, dp);
  nv = bf2f((uint16_t)(U1.w >> 16));    gl = fmaf(Gr[15], nv, gl); dp = fmaf(f1r[15], nv, dp);
}

// group2 single dot
__device__ __forceinline__ float dotu16(const float4& A0, const float4& A1,
                                        const float4& A2v, const float4& A3,
                                        const float* u16r) {
  float tp = 0.f;
  tp = fmaf(u16r[0], A0.x, tp);   tp = fmaf(u16r[1], A0.y, tp);
  tp = fmaf(u16r[2], A0.z, tp);   tp = fmaf(u16r[3], A0.w, tp);
  tp = fmaf(u16r[4], A1.x, tp);   tp = fmaf(u16r[5], A1.y, tp);
  tp = fmaf(u16r[6], A1.z, tp);   tp = fmaf(u16r[7], A1.w, tp);
  tp = fmaf(u16r[8], A2v.x, tp);  tp = fmaf(u16r[9], A2v.y, tp);
  tp = fmaf(u16r[10], A2v.z, tp); tp = fmaf(u16r[11], A2v.w, tp);
  tp = fmaf(u16r[12], A3.x, tp);  tp = fmaf(u16r[13], A3.y, tp);
  tp = fmaf(u16r[14], A3.z, tp);  tp = fmaf(u16r[15], A3.w, tp);
  return tp;
}

// ---------------- prep: SoA xyz + norms + AoS candidate float4s ----------------
__global__ __launch_bounds__(256) void k_prep_xyz(const void* xyz1, const void* xyz2,
                                                  u16p probe, float* ws, int off_aos) {
  int f32m = detect_f32(probe);
  int t = blockIdx.x * 256 + threadIdx.x;
  int b = t >> 12, n = t & (NN - 1);
  int base = b * 3 * NN + n;
  float x1 = ldi(xyz1, base, f32m), y1 = ldi(xyz1, base + NN, f32m), z1 = ldi(xyz1, base + 2 * NN, f32m);
  float x2 = ldi(xyz2, base, f32m), y2 = ldi(xyz2, base + NN, f32m), z2 = ldi(xyz2, base + 2 * NN, f32m);
  float* x1f = ws + OFF_XYZ1F;
  float* x2f = ws + OFF_XYZ2F;
  x1f[base] = x1; x1f[base + NN] = y1; x1f[base + 2 * NN] = z1;
  x2f[base] = x2; x2f[base + NN] = y2; x2f[base + 2 * NN] = z2;
  float n1v = __fadd_rn(__fadd_rn(__fmul_rn(x1, x1), __fmul_rn(y1, y1)), __fmul_rn(z1, z1));
  float n2v = __fadd_rn(__fadd_rn(__fmul_rn(x2, x2), __fmul_rn(y2, y2)), __fmul_rn(z2, z2));
  ws[OFF_N1 + t] = n1v;
  ws[OFF_N2 + t] = n2v;
  ((float4*)(ws + off_aos))[t]          = make_float4(x2, y2, z2, n2v);  // which=0 cands
  ((float4*)(ws + off_aos + 65536))[t]  = make_float4(x1, y1, z1, n1v);  // which=1 cands
}

// ---------------- transpose feat2 ----------------
__global__ __launch_bounds__(256) void k_transpose(const void* feat2, u16p probe,
                                                   float* ws, int f2cap) {
  __shared__ float tile[64][65];
  int f32m = detect_f32(probe);
  int b = blockIdx.x >> 6;
  int n0 = (blockIdx.x & 63) * 64;
  int tx = threadIdx.x & 63, ty = threadIdx.x >> 6;
#pragma unroll
  for (int i = 0; i < 16; ++i) {
    int c = i * 4 + ty;
    tile[c][tx] = ldi(feat2, (b * 64 + c) * NN + n0 + tx, f32m);
  }
  __syncthreads();
#pragma unroll
  for (int i = 0; i < 16; ++i) {
    int nl = i * 4 + ty;
    size_t di = (size_t)(b * NN + n0 + nl) * 64 + tx;
    float v = tile[tx][nl];
    if (f2cap) ((float*)(ws + OFF_F2T))[di] = v;
    else       ((uint16_t*)(ws + OFF_F2T))[di] = f2bf(v);
  }
}

// ---------------- KNN: wave-per-query, AoS loads, subsample-threshold ----------------
#define KCAP 320
__device__ __forceinline__ float knn_dist4(float4 cc, float qx, float qy, float qz, float q2) {
  float cross = __fadd_rn(__fadd_rn(__fmul_rn(qx, cc.x), __fmul_rn(qy, cc.y)),
                          __fmul_rn(qz, cc.z));
  return __fsub_rn(__fadd_rn(q2, cc.w), __fmul_rn(2.0f, cross));
}

__global__ __launch_bounds__(256) void k_knn(float* ws, int off_i12, int off_i11, int off_aos) {
  __shared__ float sd[4][KCAP];
  __shared__ int   si[4][KCAP];
  __shared__ int   eqbuf[4][16];

  int tid = threadIdx.x;
  int wv = tid >> 6, lane = tid & 63;
  int q = blockIdx.x * 4 + wv;
  int which = q >> 14;
  int b = (q >> 12) & 3;
  int n = q & (NN - 1);

  const float4* cnd = (const float4*)(ws + off_aos + (which ? 65536 : 0)) + b * NN;
  const float* qp = ws + OFF_XYZ1F + b * 3 * NN;
  float qx = qp[n], qy = qp[NN + n], qz = qp[2 * NN + n];
  float q2 = ws[OFF_N1 + b * NN + n];
  const float INF = __builtin_inff();

  float mn = INF;
#pragma unroll 4
  for (int i = 0; i < 16; ++i) {
    float d = knn_dist4(cnd[i * 64 + lane], qx, qy, qz, q2);
    mn = fminf(mn, d);
  }
  // tau0 = 16th smallest of 64 lane minima via full bitonic sort, take lane 15
  float v = mn;
#pragma unroll
  for (int k = 2; k <= 64; k <<= 1) {
#pragma unroll
    for (int j = k >> 1; j > 0; j >>= 1) {
      float other = __shfl_xor(v, j);
      bool up = ((lane & k) == 0);
      bool lower = ((lane & j) == 0);
      v = (up == lower) ? fminf(v, other) : fmaxf(v, other);
    }
  }
  float tau0 = __shfl(v, 15);

  unsigned long long below = (1ull << lane) - 1ull;
  int c = 0;
#pragma unroll 2
  for (int i = 0; i < 64; ++i) {
    int j = i * 64 + lane;
    float d = knn_dist4(cnd[j], qx, qy, qz, q2);
    bool sel = (d <= tau0);
    unsigned long long msk = __ballot(sel);
    int pos = c + __popcll(msk & below);
    if (sel && pos < KCAP) { sd[wv][pos] = d; si[wv][pos] = j; }
    c += __popcll(msk);
  }
  if (c > KCAP) c = KCAP;   // ~e^-50 event; clamp for safety
  __syncthreads();

  float ch[5];
#pragma unroll
  for (int t = 0; t < 5; ++t) ch[t] = INF;
#pragma unroll
  for (int t = 0; t < 5; ++t) {
    int p = t * 64 + lane;
    float x = (p < c) ? sd[wv][p] : INF;
#pragma unroll
    for (int u = 0; u < 5; ++u) {
      float lo = fminf(ch[u], x);
      x = fmaxf(ch[u], x);
      ch[u] = lo;
    }
  }
  // 16 extraction rounds; wave-min via DPP (r8: value-level bit-exact vs shfl_xor
  // butterfly — same multiset, fmin order-invariant, no NaNs/-0 in distances)
  float tau = 0.f;
  {
    float h = ch[0];
#pragma unroll 1
    for (int r = 0; r < 16; ++r) {
      float ms = wave_min_bcast(h);
      if (r == 15) tau = ms;
      unsigned long long win = __ballot(h == ms);
      int winner = __ffsll(win) - 1;
      if (lane == winner) {
        ch[0] = ch[1]; ch[1] = ch[2]; ch[2] = ch[3]; ch[3] = ch[4]; ch[4] = INF;
        h = ch[0];
      }
    }
  }

  uint16_t* outp = (uint16_t*)(ws + (which ? off_i11 : off_i12)) + (size_t)(b * NN + n) * SS;
  int c1 = 0, eqc = 0;
#pragma unroll
  for (int t = 0; t < 5; ++t) {
    int p = t * 64 + lane;
    bool act = (p < c);
    float d = act ? sd[wv][p] : INF;
    int j = act ? si[wv][p] : 0;
    bool lt = act && (d < tau);
    bool eq = act && (d == tau);
    unsigned long long mlt = __ballot(lt);
    unsigned long long meq = __ballot(eq);
    int pl = __popcll(mlt & below);
    if (lt) outp[c1 + pl] = (uint16_t)j;
    int pe = __popcll(meq & below);
    if (eq && (eqc + pe) < 16) eqbuf[wv][eqc + pe] = j;
    c1 += __popcll(mlt);
    eqc += __popcll(meq);
  }
  __syncthreads();
  int need = 16 - c1;
  if (lane < need) outp[c1 + lane] = (uint16_t)eqbuf[wv][lane];
}

// ---------------- fold: algebraic precomputes + feat2 norms (66 blocks) ----------------
__global__ __launch_bounds__(256) void k_fold(
    const void* w_q1, const void* w_k1, const void* w_v1, const void* w_mlp1,
    const void* w_pos1, const void* b_pos1, const void* w_q2, const void* w_k2,
    u16p probe, float* ws, int f2cap) {
  int f32m = detect_f32(probe);
  int tid = threadIdx.x;

  if (blockIdx.x >= 2) {
    int p = (blockIdx.x - 2) * 256 + tid;
    const float* f2f32 = (const float*)(ws + OFF_F2T);
    const uint16_t* f2u16 = (const uint16_t*)(ws + OFF_F2T);
    size_t row = (size_t)p * 64;
    float acc = 0.f;
#pragma unroll 8
    for (int c = 0; c < 64; ++c) {
      float v = f2cap ? f2f32[row + c] : bf2f(f2u16[row + c]);
      acc = fmaf(v, v, acc);
    }
    ws[OFF_NB2 + p] = acc;
    return;
  }

  __shared__ float lA[4096];
  __shared__ float lB[2048];   // lW1[0:1024], lM[1024:2048]
  if (blockIdx.x == 1) {
    __shared__ float lQ[4096];
    for (int i = tid; i < 4096; i += 256) { lA[i] = ldi(w_k2, i, f32m); lQ[i] = ldi(w_q2, i, f32m); }
    __syncthreads();
    for (int i = tid; i < 4096; i += 256) {
      int c = i >> 6, o = i & 63;
      float a0 = 0.f, a1 = 0.f, a2 = 0.f, a3 = 0.f;
      for (int a = 0; a < 64; a += 4) {
        a0 = fmaf(lA[a * 64 + o],       lQ[a * 64 + c],       a0);
        a1 = fmaf(lA[(a + 1) * 64 + o], lQ[(a + 1) * 64 + c], a1);
        a2 = fmaf(lA[(a + 2) * 64 + o], lQ[(a + 2) * 64 + c], a2);
        a3 = fmaf(lA[(a + 3) * 64 + o], lQ[(a + 3) * 64 + c], a3);
      }
      ws[OFF_C2 + i] = (a0 + a1) + (a2 + a3);
    }
    return;
  }

  float* lW1 = lB;
  float* lM  = lB + 1024;
  for (int i = tid; i < 1024; i += 256) lW1[i] = ldi(w_mlp1, i, f32m);   // [h][m]
  for (int i = tid; i < 4096; i += 256) lA[i] = ldi(w_k1, i, f32m);      // [m][o]
  __syncthreads();
  for (int i = tid; i < 1024; i += 256) {       // M[h][o] = W1.Wk
    int hh = i >> 6, o = i & 63;
    float acc = 0.f;
    for (int m = 0; m < 64; ++m) acc = fmaf(lW1[hh * 64 + m], lA[m * 64 + o], acc);
    lM[i] = acc;
  }
  __syncthreads();
  float a2acc[4];
  for (int i = tid; i < 4096; i += 256) lA[i] = ldi(w_q1, i, f32m);      // [o][c]
  __syncthreads();
  for (int k = 0; k < 4; ++k) {
    int i = tid + k * 256;
    int c = i >> 4, hh = i & 15;
    float acc = 0.f;
    for (int o = 0; o < 64; ++o) acc = fmaf(lW1[hh * 64 + o], lA[o * 64 + c], acc);
    a2acc[k] = acc;
  }
  __syncthreads();
  for (int i = tid; i < 4096; i += 256) { int o = i >> 6, c = i & 63; lA[o * 64 + c] = ldi(w_v1, o * 131 + c, f32m); }
  __syncthreads();
  for (int k = 0; k < 4; ++k) {
    int i = tid + k * 256;
    int c = i >> 4, hh = i & 15;
    float acc = 0.f;
    for (int o = 0; o < 64; ++o) acc = fmaf(lM[hh * 64 + o], lA[o * 64 + c], acc);
    ws[OFF_A2 + i] = a2acc[k] - acc;
  }
  __syncthreads();
  for (int i = tid; i < 4096; i += 256) { int o = i >> 6, c = i & 63; lA[o * 64 + c] = ldi(w_v1, o * 131 + 64 + c, f32m); }
  __syncthreads();
  for (int i = tid; i < 1024; i += 256) {       // G[c][h] = M*Wvb
    int c = i >> 4, hh = i & 15;
    float acc = 0.f;
    for (int o = 0; o < 64; ++o) acc = fmaf(lM[hh * 64 + o], lA[o * 64 + c], acc);
    ws[OFF_G + i] = acc;
  }
  if (tid < 16) {
    int hh = tid;
    float p0 = 0.f, p1 = 0.f, p2 = 0.f, p3 = 0.f, p4 = 0.f, pb = 0.f;
    for (int o = 0; o < 64; ++o) {
      float m = lM[hh * 64 + o];
      p0 = fmaf(m, ldi(w_pos1, o * 5 + 0, f32m), p0);
      p1 = fmaf(m, ldi(w_pos1, o * 5 + 1, f32m), p1);
      p2 = fmaf(m, ldi(w_v1, o * 131 + 128, f32m) + ldi(w_pos1, o * 5 + 2, f32m), p2);
      p3 = fmaf(m, ldi(w_v1, o * 131 + 129, f32m) + ldi(w_pos1, o * 5 + 3, f32m), p3);
      p4 = fmaf(m, ldi(w_v1, o * 131 + 130, f32m) + ldi(w_pos1, o * 5 + 4, f32m), p4);
      pb = fmaf(m, ldi(b_pos1, o, f32m), pb);
    }
    ws[OFF_P5 + hh] = p0; ws[OFF_P5 + 16 + hh] = p1; ws[OFF_P5 + 32 + hh] = p2;
    ws[OFF_P5 + 48 + hh] = p3; ws[OFF_P5 + 64 + hh] = p4;
    ws[OFF_MBP + hh] = pb;
  }
}

// shared dual-step online-softmax epilogue for group1's s-loop.
// Consumes gl0,dp0,nb0 (step s) and gl1,dp1,nb1 (step s+1); updates m,l,anb,axa,aya,aza.
// r9: within-16 logit reduce via sum16_dpp (bit-identical to xor1/2/4/8 butterfly,
// see sum16_dpp comment); cross-16 stages stay as shfl_xor.
#define G1_EPI()                                                        \
      gl0 += __shfl_xor(gl0, 16); dp0 += __shfl_xor(dp0, 16);           \
      gl1 += __shfl_xor(gl1, 16); dp1 += __shfl_xor(dp1, 16);           \
      gl0 += __shfl_xor(gl0, 32); dp0 += __shfl_xor(dp0, 32);           \
      gl1 += __shfl_xor(gl1, 32); dp1 += __shfl_xor(dp1, 32);           \
      float4 xd0 = xds4[w][s];                                          \
      float4 xd1 = xds4[w][s + 1];                                      \
      float fn0 = sqrtf(fmaxf(f1n2 - 2.f * dp0 + snb2[w][s], 0.f));     \
      float fn1 = sqrtf(fmaxf(f1n2 - 2.f * dp1 + snb2[w][s + 1], 0.f)); \
      float p50 = p5a * fn0;                                            \
      p50 = fmaf(p5b, xd0.w, p50); p50 = fmaf(p5c, xd0.x, p50);         \
      p50 = fmaf(p5d, xd0.y, p50); p50 = fmaf(p5e, xd0.z, p50);         \
      float p51 = p5a * fn1;                                            \
      p51 = fmaf(p5b, xd1.w, p51); p51 = fmaf(p5c, xd1.x, p51);         \
      p51 = fmaf(p5d, xd1.y, p51); p51 = fmaf(p5e, xd1.z, p51);         \
      float r0 = fmaxf(tb - gl0 - p50, 0.f) * w2r;                      \
      float r1 = fmaxf(tb - gl1 - p51, 0.f) * w2r;                      \
      r0 = sum16_dpp(r0); r1 = sum16_dpp(r1);                           \
      float mnv = fmaxf(fmaxf(m, r0), r1);                              \
      float sc = __expf(m - mnv);                                       \
      float e0 = __expf(r0 - mnv);                                      \
      float e1 = __expf(r1 - mnv);                                      \
      l = fmaf(l, sc, e0 + e1);                                         \
      anb = fmaf(e1, nb1, fmaf(e0, nb0, anb * sc));                     \
      axa = fmaf(e1, xd1.x, fmaf(e0, xd0.x, axa * sc));                 \
      aya = fmaf(e1, xd1.y, fmaf(e0, xd0.y, aya * sc));                 \
      aza = fmaf(e1, xd1.z, fmaf(e0, xd0.z, aza * sc));                 \
      m = mnv;

#define G1_LOADF(A0, A1, A2r, A3, NBV, J) {                             \
      size_t row_ = (size_t)(b * NN + (J)) * 64;                        \
      const float4* r4_ = (const float4*)(f2f32 + row_) + part * 4;     \
      A0 = r4_[0]; A1 = r4_[1]; A2r = r4_[2]; A3 = r4_[3];              \
      NBV = f2f32[row_ + o]; }

#define G1_LOADB(U0, U1, NBU, J) {                                      \
      size_t row_ = (size_t)(b * NN + (J)) * 64;                        \
      const uint4* r4_ = (const uint4*)(f2u16 + row_) + part * 2;       \
      U0 = r4_[0]; U1 = r4_[1]; NBU = f2u16[row_ + o]; }

// ---------------- group1: per-lane slice loads, depth-2 pipelined gather loop ----------------
// launch_bounds (512,2): 2 BLOCKS/CU (CUDA semantics, r8 post-mortem) => 128-VGPR cap.
__global__ __launch_bounds__(512, 2) void k_group1(
    const void* feat1, const void* w_v1, const void* w_mlp2,
    u16p probe, float* ws, int off_p2n, int off_i12, int f2cap) {
  __shared__ float s_wva[4096];    // [c][o]
  __shared__ float s_wvb[4096];    // [c][o]
  __shared__ float s_wvx[192];
  __shared__ float s_A2[1088];     // [c*17+h] padded
  __shared__ float s_G[1088];      // [c*17+h] padded
  __shared__ float s_P5[80];
  __shared__ float s_MBP[16];
  __shared__ float s_w2[16];
  __shared__ float f1s[8][64];
  __shared__ float4 xds4[8][16];   // per s: (dx,dy,dz,norm)
  __shared__ float snb2[8][16];
  __shared__ int   idxs[8][16];

  int f32m = detect_f32(probe);
  int tid = threadIdx.x;
  for (int i = tid; i < 4096; i += 512) {
    int c = i >> 6, o = i & 63;
    s_wva[i] = ldi(w_v1, o * 131 + c, f32m);
    s_wvb[i] = ldi(w_v1, o * 131 + 64 + c, f32m);
  }
  if (tid < 192) { int j = tid >> 6, o = tid & 63; s_wvx[tid] = ldi(w_v1, o * 131 + 128 + j, f32m); }
  for (int i = tid; i < 1024; i += 512) {
    int c = i >> 4, h = i & 15;
    s_A2[c * 17 + h] = ws[OFF_A2 + i];
    s_G[c * 17 + h] = ws[OFF_G + i];
  }
  if (tid < 80) s_P5[tid] = ws[OFF_P5 + tid];
  if (tid < 16) { s_MBP[tid] = ws[OFF_MBP + tid]; s_w2[tid] = ldi(w_mlp2, tid, f32m); }

  int w = tid >> 6, o = tid & 63;
  int g = blockIdx.x * 8 + w;
  int b = g >> 12, n = g & (NN - 1);
  const float* x1f = ws + OFF_XYZ1F + b * 3 * NN;
  const float* x2f = ws + OFF_XYZ2F + b * 3 * NN;
  const uint16_t* idx12 = (const uint16_t*)(ws + off_i12) + (size_t)(b * NN + n) * SS;
  const float* f2f32 = (const float*)(ws + OFF_F2T);
  const uint16_t* f2u16 = (const uint16_t*)(ws + OFF_F2T);

  float f1o = ldi(feat1, (b * 64 + o) * NN + n, f32m);
  f1s[w][o] = f1o;
  float qx = x1f[n], qy = x1f[NN + n], qz = x1f[2 * NN + n];
  if (o < 16) {
    int j = (int)idx12[o];
    idxs[w][o] = j;
    float dx = __fsub_rn(qx, x2f[j]);
    float dy = __fsub_rn(qy, x2f[NN + j]);
    float dz = __fsub_rn(qz, x2f[2 * NN + j]);
    xds4[w][o] = make_float4(dx, dy, dz, sqrtf(dx * dx + dy * dy + dz * dz));
    snb2[w][o] = ws[OFF_NB2 + b * NN + j];
  }
  __syncthreads();   // only block barrier; below: regs/shfl/read-only LDS

  int h = o & 15, part = o >> 4;
  float Gr[16], f1r[16];
#pragma unroll
  for (int i = 0; i < 16; ++i) {
    int c = part * 16 + i;
    Gr[i] = s_G[c * 17 + h];
    f1r[i] = f1s[w][c];
  }
  float p5a = s_P5[h], p5b = s_P5[16 + h], p5c = s_P5[32 + h], p5d = s_P5[48 + h], p5e = s_P5[64 + h];
  float w2r = s_w2[h];

  // f1n2: within-16 stages via DPP (bit-identical, see sum16_dpp), cross-16 via shfl
  float f1n2 = f1o * f1o;
  f1n2 = sum16_dpp(f1n2);
  f1n2 += __shfl_xor(f1n2, 16);
  f1n2 += __shfl_xor(f1n2, 32);
  float v0 = 0.f, v1 = 0.f, v2 = 0.f, v3 = 0.f;
#pragma unroll
  for (int c = 0; c < 64; c += 4) {
    v0 = fmaf(s_wva[c * 64 + o],       f1s[w][c],     v0);
    v1 = fmaf(s_wva[(c + 1) * 64 + o], f1s[w][c + 1], v1);
    v2 = fmaf(s_wva[(c + 2) * 64 + o], f1s[w][c + 2], v2);
    v3 = fmaf(s_wva[(c + 3) * 64 + o], f1s[w][c + 3], v3);
  }
  float vb = (v0 + v1) + (v2 + v3);
  float tb = 0.f;
#pragma unroll
  for (int i = 0; i < 16; ++i) {
    int c = part * 16 + i;
    tb = fmaf(s_A2[c * 17 + h], f1s[w][c], tb);
  }
  tb += __shfl_xor(tb, 16);
  tb += __shfl_xor(tb, 32);
  tb -= s_MBP[h];

  float m = -__builtin_inff(), l = 0.f;
  float anb = 0.f, axa = 0.f, aya = 0.f, aza = 0.f;

  if (f2cap) {
    // f32 rows: depth-2 pipeline, step-2 merged softmax
    float4 A0, A1, A2r, A3, B0, B1, B2r, B3;
    float nbAv, nbBv;
    G1_LOADF(A0, A1, A2r, A3, nbAv, idxs[w][0]);
#pragma unroll 1
    for (int s = 0; s < SS; s += 2) {
      G1_LOADF(B0, B1, B2r, B3, nbBv, idxs[w][s + 1]);          // issue s+1 row
      float gl0 = 0.f, dp0 = 0.f;
      dot16f(A0, A1, A2r, A3, Gr, f1r, gl0, dp0);               // consume s row
      float nb0 = nbAv;
      {
        int jn = (s + 2 < SS) ? idxs[w][s + 2] : idxs[w][0];
        G1_LOADF(A0, A1, A2r, A3, nbAv, jn);                    // issue s+2 row
      }
      float gl1 = 0.f, dp1 = 0.f;
      dot16f(B0, B1, B2r, B3, Gr, f1r, gl1, dp1);               // consume s+1 row
      float nb1 = nbBv;
      G1_EPI();
    }
  } else {
    // bf16 rows: same structure
    uint4 UA0, UA1, UB0, UB1;
    uint16_t nbAu, nbBu;
    G1_LOADB(UA0, UA1, nbAu, idxs[w][0]);
#pragma unroll 1
    for (int s = 0; s < SS; s += 2) {
      G1_LOADB(UB0, UB1, nbBu, idxs[w][s + 1]);
      float gl0 = 0.f, dp0 = 0.f;
      dot16b(UA0, UA1, Gr, f1r, gl0, dp0);
      float nb0 = bf2f(nbAu);
      {
        int jn = (s + 2 < SS) ? idxs[w][s + 2] : idxs[w][0];
        G1_LOADB(UA0, UA1, nbAu, jn);
      }
      float gl1 = 0.f, dp1 = 0.f;
      dot16b(UB0, UB1, Gr, f1r, gl1, dp1);
      float nb1 = bf2f(nbBu);
      G1_EPI();
    }
  }

  float invl = 1.f / l;
  anb *= invl; axa *= invl; aya *= invl; aza *= invl;
  float o0 = vb, o1 = 0.f, o2 = 0.f, o3 = 0.f;
#pragma unroll
  for (int c = 0; c < 64; c += 4) {
    o0 = fmaf(s_wvb[c * 64 + o],       __shfl(anb, c),     o0);
    o1 = fmaf(s_wvb[(c + 1) * 64 + o], __shfl(anb, c + 1), o1);
    o2 = fmaf(s_wvb[(c + 2) * 64 + o], __shfl(anb, c + 2), o2);
    o3 = fmaf(s_wvb[(c + 3) * 64 + o], __shfl(anb, c + 3), o3);
  }
  float acc = (o0 + o1) + (o2 + o3);
  acc = fmaf(s_wvx[o], axa, acc);
  acc = fmaf(s_wvx[64 + o], aya, acc);
  acc = fmaf(s_wvx[128 + o], aza, acc);
  float res = acc >= 0.f ? acc : 0.1f * acc;   // leaky 0.1
  ws[off_p2n + (size_t)(b * NN + n) * 64 + o] = res;
}

#define G2_LOAD(A0, A1, A2v, A3, NBV, J) {                              \
      size_t row_ = (size_t)(b * NN + (J)) * 64;                        \
      const float4* r4_ = (const float4*)(p2t + row_) + part * 4;       \
      A0 = r4_[0]; A1 = r4_[1]; A2v = r4_[2]; A3 = r4_[3];              \
      NBV = p2t[row_ + o]; }

// ---------------- group2: per-lane slice loads, depth-2 pipelined gather loop ----------------
__global__ __launch_bounds__(512, 2) void k_group2(
    const void* w_v2, const void* w_pos2, const void* b_pos2,
    u16p probe, float* ws, void* outp, int off_p2n, int off_i11) {
  __shared__ float s_C2[4096];    // [c][o]
  __shared__ float s_wv2[4096];   // [c][o]
  __shared__ float s_wp2t[256];   // [p][o]
  __shared__ float s_bp2[64];
  __shared__ float4 xds4[8][16];
  __shared__ int   idxs[8][16];
  __shared__ float souts[8][64];

  int f32m = detect_f32(probe);
  int tid = threadIdx.x;
  for (int i = tid; i < 4096; i += 512) {
    int c = i >> 6, o = i & 63;
    s_C2[i] = ws[OFF_C2 + i];
    s_wv2[i] = ldi(w_v2, o * 64 + c, f32m);
  }
  if (tid < 256) { int p = tid >> 6, o = tid & 63; s_wp2t[p * 64 + o] = ldi(w_pos2, o * 4 + p, f32m); }
  if (tid < 64) s_bp2[tid] = ldi(b_pos2, tid, f32m);

  int w = tid >> 6, o = tid & 63;
  int g = blockIdx.x * 8 + w;
  int b = g >> 12, n = g & (NN - 1);
  const float* p2t = ws + off_p2n;
  const float* x1f = ws + OFF_XYZ1F + b * 3 * NN;
  const uint16_t* idx11 = (const uint16_t*)(ws + off_i11) + (size_t)(b * NN + n) * SS;

  float p1o = p2t[(size_t)(b * NN + n) * 64 + o];
  float qx = x1f[n], qy = x1f[NN + n], qz = x1f[2 * NN + n];
  if (o < 16) {
    int j = (int)idx11[o];
    idxs[w][o] = j;
    float dx = __fsub_rn(qx, x1f[j]);
    float dy = __fsub_rn(qy, x1f[NN + j]);
    float dz = __fsub_rn(qz, x1f[2 * NN + j]);
    xds4[w][o] = make_float4(dx, dy, dz, sqrtf(dx * dx + dy * dy + dz * dz));
  }
  __syncthreads();

  int part = o >> 4;
  // u[o] = (Wk2^T Wq2).pts  via shfl broadcasts of p1o (once per wave)
  float u0 = 0.f, u1 = 0.f, u2 = 0.f, u3 = 0.f;
#pragma unroll
  for (int c = 0; c < 64; c += 4) {
    u0 = fmaf(s_C2[c * 64 + o],       __shfl(p1o, c),     u0);
    u1 = fmaf(s_C2[(c + 1) * 64 + o], __shfl(p1o, c + 1), u1);
    u2 = fmaf(s_C2[(c + 2) * 64 + o], __shfl(p1o, c + 2), u2);
    u3 = fmaf(s_C2[(c + 3) * 64 + o], __shfl(p1o, c + 3), u3);
  }
  float u = (u0 + u1) + (u2 + u3);
  float w4x = u * s_wp2t[o];
  float w4y = u * s_wp2t[64 + o];
  float w4z = u * s_wp2t[128 + o];
  float w4n = u * s_wp2t[192 + o];
  float ubp = u * s_bp2[o];
#pragma unroll
  for (int msk = 1; msk < 64; msk <<= 1) {
    w4x += __shfl_xor(w4x, msk);
    w4y += __shfl_xor(w4y, msk);
    w4z += __shfl_xor(w4z, msk);
    w4n += __shfl_xor(w4n, msk);
    ubp += __shfl_xor(ubp, msk);
  }
  float u16r[16];
#pragma unroll
  for (int i = 0; i < 16; ++i) u16r[i] = __shfl(u, part * 16 + i);

  float m = -__builtin_inff(), l = 0.f, anb = 0.f;
  float4 A0, A1, A2v, A3, B0, B1, B2v, B3;
  float nbAv, nbBv;
  G2_LOAD(A0, A1, A2v, A3, nbAv, idxs[w][0]);
#pragma unroll 1
  for (int s = 0; s < SS; s += 2) {
    G2_LOAD(B0, B1, B2v, B3, nbBv, idxs[w][s + 1]);             // issue s+1 row
    float tp0 = dotu16(A0, A1, A2v, A3, u16r);                  // consume s row
    float nb0 = nbAv;
    {
      int jn = (s + 2 < SS) ? idxs[w][s + 2] : idxs[w][0];
      G2_LOAD(A0, A1, A2v, A3, nbAv, jn);                       // issue s+2 row
    }
    float tp1 = dotu16(B0, B1, B2v, B3, u16r);                  // consume s+1 row
    float nb1 = nbBv;
    tp0 += __shfl_xor(tp0, 16); tp1 += __shfl_xor(tp1, 16);
    tp0 += __shfl_xor(tp0, 32); tp1 += __shfl_xor(tp1, 32);
    float4 xd0 = xds4[w][s], xd1 = xds4[w][s + 1];
    float lg0 = tp0;
    lg0 = fmaf(w4x, xd0.x, lg0);
    lg0 = fmaf(w4y, xd0.y, lg0);
    lg0 = fmaf(w4z, xd0.z, lg0);
    lg0 = fmaf(w4n, xd0.w, lg0);
    lg0 = (lg0 + ubp) * 0.125f;
    float lg1 = tp1;
    lg1 = fmaf(w4x, xd1.x, lg1);
    lg1 = fmaf(w4y, xd1.y, lg1);
    lg1 = fmaf(w4z, xd1.z, lg1);
    lg1 = fmaf(w4n, xd1.w, lg1);
    lg1 = (lg1 + ubp) * 0.125f;
    float mnv = fmaxf(fmaxf(m, lg0), lg1);
    float sc = __expf(m - mnv);
    float e0 = __expf(lg0 - mnv);
    float e1 = __expf(lg1 - mnv);
    l = fmaf(l, sc, e0 + e1);
    anb = fmaf(e1, nb1, fmaf(e0, nb0, anb * sc));
    m = mnv;
  }
  anb *= 1.f / l;
  float o0 = 0.f, o1 = 0.f, o2 = 0.f, o3 = 0.f;
#pragma unroll
  for (int c = 0; c < 64; c += 4) {
    o0 = fmaf(s_wv2[c * 64 + o],       __shfl(anb, c),     o0);
    o1 = fmaf(s_wv2[(c + 1) * 64 + o], __shfl(anb, c + 1), o1);
    o2 = fmaf(s_wv2[(c + 2) * 64 + o], __shfl(anb, c + 2), o2);
    o3 = fmaf(s_wv2[(c + 3) * 64 + o], __shfl(anb, c + 3), o3);
  }
  float acc = (o0 + o1) + (o2 + o3);
  float res = acc >= 0.f ? acc : 0.1f * acc;
  souts[w][o] = res;
  __syncthreads();   // cross-wave transpose staging
  int c = tid >> 3, nr = tid & 7;
  int n0 = (blockIdx.x * 8) & (NN - 1);
  int b0 = (blockIdx.x * 8) >> 12;
  size_t oi = (size_t)(b0 * 64 + c) * NN + n0 + nr;
  float ov = souts[nr][c];
  if (f32m) ((float*)outp)[oi] = ov;
  else      ((uint16_t*)outp)[oi] = f2bf(ov);
}

extern "C" void kernel_launch(void* const* d_in, const int* in_sizes, int n_in,
                              void* d_out, int out_size, void* d_ws, size_t ws_size,
                              hipStream_t stream) {
  const void* xyz1 = d_in[0];
  const void* feat1 = d_in[1];
  const void* xyz2 = d_in[2];
  const void* feat2 = d_in[3];
  const void* w_q1 = d_in[4];
  const void* w_k1 = d_in[5];
  const void* w_v1 = d_in[6];
  const void* w_mlp1 = d_in[7];
  const void* w_mlp2 = d_in[8];
  const void* w_pos1 = d_in[9];
  const void* b_pos1 = d_in[10];
  const void* w_q2 = d_in[11];
  const void* w_k2 = d_in[12];
  const void* w_v2 = d_in[13];
  const void* w_pos2 = d_in[14];
  const void* b_pos2 = d_in[15];
  u16p probe = (u16p)d_in[1];
  float* ws = (float*)d_ws;

  if (ws_size < WS_MIN_FLOATS * 4ull) return;

  int big = (ws_size >= 2490368ull * 4ull) ? 1 : 0;
  int f2cap   = big;
  int off_p2n = big ? 1179648 : 655360;
  int off_i12 = big ? 2228224 : 1703936;
  int off_i11 = big ? 2359296 : 1835008;
  int off_aos = off_p2n;   // AoS candidates live in (pre-group1) P2N region

  hipLaunchKernelGGL(k_prep_xyz, dim3(64), dim3(256), 0, stream, xyz1, xyz2, probe, ws, off_aos);
  hipLaunchKernelGGL(k_transpose, dim3(256), dim3(256), 0, stream, feat2, probe, ws, f2cap);
  hipLaunchKernelGGL(k_knn, dim3(8192), dim3(256), 0, stream, ws, off_i12, off_i11, off_aos);
  hipLaunchKernelGGL(k_fold, dim3(66), dim3(256), 0, stream,
                     w_q1, w_k1, w_v1, w_mlp1, w_pos1, b_pos1, w_q2, w_k2, probe, ws, f2cap);
  hipLaunchKernelGGL(k_group1, dim3(2048), dim3(512), 0, stream,
                     feat1, w_v1, w_mlp2, probe, ws, off_p2n, off_i12, f2cap);
  hipLaunchKernelGGL(k_group2, dim3(2048), dim3(512), 0, stream,
                     w_v2, w_pos2, b_pos2, probe, ws, d_out, off_p2n, off_i11);
}